// Round 3
// baseline (4503.989 us; speedup 1.0000x reference)
//
#include <hip/hip_runtime.h>
#include <math.h>

#define G 200
#define NF 128
#define EF 64

constexpr int BM = 64, BN = 64, BK = 16;

enum { E_LEAKY = 0, E_BIAS = 1 };

__device__ __forceinline__ float leakyf(float x) { return x > 0.f ? x : 0.01f * x; }
__device__ __forceinline__ float eluf(float x)   { return x > 0.f ? x : (expf(x) - 1.f); }
__device__ __forceinline__ float sigm(float x)   { return 1.f / (1.f + expf(-x)); }

// ---------------- generic tiled f32 GEMM (dense A) ----------------
// C[M,Ncol] = epi(A[M,K] @ W[K,Ncol] + bias)
template <int EPI>
__global__ __launch_bounds__(256) void gemm_k(
    const float* __restrict__ A, const float* __restrict__ W,
    const float* __restrict__ bias, float* __restrict__ C,
    int M, int K, int Ncol)
{
    __shared__ float As[BK][BM];
    __shared__ float Bs[BK][BN];
    const int bm = blockIdx.x * BM;
    const int bn = blockIdx.y * BN;
    const int tx = threadIdx.x, ty = threadIdx.y;
    const int tid = ty * 16 + tx;
    const int ar = tid >> 2, ak = (tid & 3) * 4;
    const int bk = tid >> 4, bc = (tid & 15) * 4;

    float acc[4][4] = {};

    for (int k0 = 0; k0 < K; k0 += BK) {
        float4 av = make_float4(0.f, 0.f, 0.f, 0.f);
        int r = bm + ar, kk = k0 + ak;
        if (r < M && kk < K) av = *(const float4*)&A[(size_t)r * K + kk];
        As[ak + 0][ar] = av.x; As[ak + 1][ar] = av.y;
        As[ak + 2][ar] = av.z; As[ak + 3][ar] = av.w;

        float4 bv = make_float4(0.f, 0.f, 0.f, 0.f);
        int kb = k0 + bk, cb = bn + bc;
        if (kb < K && cb < Ncol) bv = *(const float4*)&W[(size_t)kb * Ncol + cb];
        *(float4*)&Bs[bk][bc] = bv;

        __syncthreads();
#pragma unroll
        for (int kk2 = 0; kk2 < BK; ++kk2) {
            float4 a4 = *(const float4*)&As[kk2][ty * 4];
            float4 b4 = *(const float4*)&Bs[kk2][tx * 4];
#define FMA4(i, ax)                                  \
            acc[i][0] = fmaf(ax, b4.x, acc[i][0]);   \
            acc[i][1] = fmaf(ax, b4.y, acc[i][1]);   \
            acc[i][2] = fmaf(ax, b4.z, acc[i][2]);   \
            acc[i][3] = fmaf(ax, b4.w, acc[i][3]);
            FMA4(0, a4.x) FMA4(1, a4.y) FMA4(2, a4.z) FMA4(3, a4.w)
#undef FMA4
        }
        __syncthreads();
    }

#pragma unroll
    for (int i = 0; i < 4; ++i) {
        int r = bm + ty * 4 + i;
        if (r >= M) continue;
#pragma unroll
        for (int j = 0; j < 4; ++j) {
            int cc = bn + tx * 4 + j;
            if (cc >= Ncol) continue;
            float v = acc[i][j] + bias[cc];
            C[(size_t)r * Ncol + cc] = (EPI == E_LEAKY) ? leakyf(v) : v;
        }
    }
}

// ---------------- hd[n] = hv[n,:] . e2W[0:200] ----------------
__global__ __launch_bounds__(256) void hd_k(
    const float* __restrict__ hv, const float* __restrict__ e2W,
    float* __restrict__ hd, int Nn)
{
    int wid = blockIdx.x * 4 + (threadIdx.x >> 6);
    int lane = threadIdx.x & 63;
    if (wid >= Nn) return;
    float s = 0.f;
    for (int j = lane; j < G; j += 64) s += hv[(size_t)wid * G + j] * e2W[j];
    for (int off = 32; off; off >>= 1) s += __shfl_down(s, off);
    if (lane == 0) hd[wid] = s;
}

// ------------- edgeA: he1 (recomputed) -> logits + softmax denom -------------
__global__ __launch_bounds__(256) void edgeA_k(
    const float* __restrict__ node, const float* __restrict__ edge,
    const int* __restrict__ src, const int* __restrict__ dst,
    const float* __restrict__ W1, const float* __restrict__ b1,
    const float* __restrict__ e2W, const float* __restrict__ e2b,
    const float* __restrict__ hd,
    float* __restrict__ lg, float* __restrict__ sden, int E)
{
    __shared__ float As[BK][BM];
    __shared__ float Bs[BK][BN];
    __shared__ float rowacc[BM];

    const int eb = blockIdx.x * BM;
    const int tx = threadIdx.x, ty = threadIdx.y;
    const int tid = ty * 16 + tx;
    const int ar = tid >> 2, ak = (tid & 3) * 4;
    const int bk = tid >> 4, bc = (tid & 15) * 4;

    if (tid < BM) rowacc[tid] = 0.f;
    __syncthreads();

    const int re = eb + ar;
    const int se = (re < E) ? src[re] : 0;

    for (int cb = 0; cb < 4; ++cb) {
        float acc[4][4] = {};
        for (int k0 = 0; k0 < NF + EF; k0 += BK) {
            int kk = k0 + ak;
            float4 av = make_float4(0.f, 0.f, 0.f, 0.f);
            if (re < E) {
                if (kk < NF) av = *(const float4*)&node[(size_t)se * NF + kk];
                else         av = *(const float4*)&edge[(size_t)re * EF + (kk - NF)];
            }
            As[ak + 0][ar] = av.x; As[ak + 1][ar] = av.y;
            As[ak + 2][ar] = av.z; As[ak + 3][ar] = av.w;

            float4 bv = make_float4(0.f, 0.f, 0.f, 0.f);
            int kb = k0 + bk, cc = cb * BN + bc;
            if (cc < G) bv = *(const float4*)&W1[(size_t)kb * G + cc];
            *(float4*)&Bs[bk][bc] = bv;

            __syncthreads();
#pragma unroll
            for (int kk2 = 0; kk2 < BK; ++kk2) {
                float4 a4 = *(const float4*)&As[kk2][ty * 4];
                float4 b4 = *(const float4*)&Bs[kk2][tx * 4];
#define FMA4(i, ax)                                  \
                acc[i][0] = fmaf(ax, b4.x, acc[i][0]);\
                acc[i][1] = fmaf(ax, b4.y, acc[i][1]);\
                acc[i][2] = fmaf(ax, b4.z, acc[i][2]);\
                acc[i][3] = fmaf(ax, b4.w, acc[i][3]);
                FMA4(0, a4.x) FMA4(1, a4.y) FMA4(2, a4.z) FMA4(3, a4.w)
#undef FMA4
            }
            __syncthreads();
        }
        float p[4] = {0.f, 0.f, 0.f, 0.f};
#pragma unroll
        for (int i = 0; i < 4; ++i) {
#pragma unroll
            for (int j = 0; j < 4; ++j) {
                int cg = cb * BN + tx * 4 + j;
                if (cg < G) {
                    float v = leakyf(acc[i][j] + b1[cg]);
                    p[i] += v * e2W[G + cg];
                }
            }
        }
#pragma unroll
        for (int i = 0; i < 4; ++i) {
            p[i] += __shfl_xor(p[i], 1);
            p[i] += __shfl_xor(p[i], 2);
            p[i] += __shfl_xor(p[i], 4);
            p[i] += __shfl_xor(p[i], 8);
            if (tx == 0) rowacc[ty * 4 + i] += p[i];
        }
        __syncthreads();
    }

    if (tid < BM) {
        int e = eb + tid;
        if (e < E) {
            float l = leakyf(rowacc[tid] + hd[dst[e]] + e2b[0]);
            lg[e] = l;
            atomicAdd(&sden[dst[e]], expf(l));
        }
    }
}

// ------------- edgeB: he1 (recomputed) -> et GEMM -> a*val scatter into c -------------
__global__ __launch_bounds__(256) void edgeB_k(
    const float* __restrict__ node, const float* __restrict__ edge,
    const int* __restrict__ src, const int* __restrict__ dst,
    const float* __restrict__ W1, const float* __restrict__ b1,
    const float* __restrict__ etW, const float* __restrict__ etb,
    const float* __restrict__ lg, const float* __restrict__ sden,
    float* __restrict__ cacc, int E)
{
    __shared__ float As[BK][BM];
    __shared__ float Bs[BK][BN];
    __shared__ float Hc[BM][BN + 4];
    __shared__ float Bs2[BK][256];

    const int eb = blockIdx.x * BM;
    const int tx = threadIdx.x, ty = threadIdx.y;
    const int tid = ty * 16 + tx;
    const int ar = tid >> 2, ak = (tid & 3) * 4;
    const int bk = tid >> 4, bc = (tid & 15) * 4;

    const int re = eb + ar;
    const int se = (re < E) ? src[re] : 0;

    float acc_et[4][4][4] = {};

    for (int kb = 0; kb < 4; ++kb) {
        float acc[4][4] = {};
        for (int k0 = 0; k0 < NF + EF; k0 += BK) {
            int kk = k0 + ak;
            float4 av = make_float4(0.f, 0.f, 0.f, 0.f);
            if (re < E) {
                if (kk < NF) av = *(const float4*)&node[(size_t)se * NF + kk];
                else         av = *(const float4*)&edge[(size_t)re * EF + (kk - NF)];
            }
            As[ak + 0][ar] = av.x; As[ak + 1][ar] = av.y;
            As[ak + 2][ar] = av.z; As[ak + 3][ar] = av.w;

            float4 bv = make_float4(0.f, 0.f, 0.f, 0.f);
            int kwr = k0 + bk, cc = kb * BN + bc;
            if (cc < G) bv = *(const float4*)&W1[(size_t)kwr * G + cc];
            *(float4*)&Bs[bk][bc] = bv;

            __syncthreads();
#pragma unroll
            for (int kk2 = 0; kk2 < BK; ++kk2) {
                float4 a4 = *(const float4*)&As[kk2][ty * 4];
                float4 b4 = *(const float4*)&Bs[kk2][tx * 4];
#define FMA4(i, ax)                                  \
                acc[i][0] = fmaf(ax, b4.x, acc[i][0]);\
                acc[i][1] = fmaf(ax, b4.y, acc[i][1]);\
                acc[i][2] = fmaf(ax, b4.z, acc[i][2]);\
                acc[i][3] = fmaf(ax, b4.w, acc[i][3]);
                FMA4(0, a4.x) FMA4(1, a4.y) FMA4(2, a4.z) FMA4(3, a4.w)
#undef FMA4
            }
            __syncthreads();
        }
#pragma unroll
        for (int i = 0; i < 4; ++i)
#pragma unroll
            for (int j = 0; j < 4; ++j) {
                int cg = kb * BN + tx * 4 + j;
                Hc[ty * 4 + i][tx * 4 + j] =
                    (cg < G) ? leakyf(acc[i][j] + b1[cg]) : 0.f;
            }
        __syncthreads();

        for (int k0s = 0; k0s < BN; k0s += BK) {
            for (int q = tid; q < 16 * 64; q += 256) {
                int kr = q >> 6, c4 = (q & 63) * 4;
                int rg = kb * BN + k0s + kr;
                float4 bv = make_float4(0.f, 0.f, 0.f, 0.f);
                if (rg < G && c4 < G) bv = *(const float4*)&etW[(size_t)rg * G + c4];
                *(float4*)&Bs2[kr][c4] = bv;
            }
            __syncthreads();
#pragma unroll
            for (int kk2 = 0; kk2 < BK; ++kk2) {
                float a0 = Hc[ty * 4 + 0][k0s + kk2];
                float a1 = Hc[ty * 4 + 1][k0s + kk2];
                float a2 = Hc[ty * 4 + 2][k0s + kk2];
                float a3 = Hc[ty * 4 + 3][k0s + kk2];
#pragma unroll
                for (int nb = 0; nb < 4; ++nb) {
                    float4 b4 = *(const float4*)&Bs2[kk2][nb * BN + tx * 4];
#define ET4(i, ax)                                             \
                    acc_et[nb][i][0] = fmaf(ax, b4.x, acc_et[nb][i][0]); \
                    acc_et[nb][i][1] = fmaf(ax, b4.y, acc_et[nb][i][1]); \
                    acc_et[nb][i][2] = fmaf(ax, b4.z, acc_et[nb][i][2]); \
                    acc_et[nb][i][3] = fmaf(ax, b4.w, acc_et[nb][i][3]);
                    ET4(0, a0) ET4(1, a1) ET4(2, a2) ET4(3, a3)
#undef ET4
                }
            }
            __syncthreads();
        }
    }

#pragma unroll
    for (int i = 0; i < 4; ++i) {
        int e = eb + ty * 4 + i;
        if (e >= E) continue;
        int d = dst[e];
        float ae = expf(lg[e]) / sden[d];
#pragma unroll
        for (int nb = 0; nb < 4; ++nb)
#pragma unroll
            for (int j = 0; j < 4; ++j) {
                int col = nb * BN + tx * 4 + j;
                if (col < G)
                    atomicAdd(&cacc[(size_t)d * G + col],
                              ae * (acc_et[nb][i][j] + etb[col]));
            }
    }
}

// ------------- fused GRU: out = relu(GRU(elu(X), H)) -------------
__global__ __launch_bounds__(256) void grufuse_k(
    const float* __restrict__ X, const float* __restrict__ H,
    const float* __restrict__ Wx, const float* __restrict__ Wh,
    const float* __restrict__ bx, const float* __restrict__ bh,
    float* __restrict__ OUT, int M)
{
    __shared__ float Ax[BK][BM];
    __shared__ float Ah[BK][BM];
    __shared__ float Bx[3][BK][BN];
    __shared__ float Bh[3][BK][BN];

    const int bm = blockIdx.x * BM;
    const int bn = blockIdx.y * BN;
    const int tx = threadIdx.x, ty = threadIdx.y;
    const int tid = ty * 16 + tx;
    const int ar = tid >> 2, ak = (tid & 3) * 4;
    const int bk = tid >> 4, bc = (tid & 15) * 4;

    float accx[3][4][4] = {};
    float acch[3][4][4] = {};

    for (int k0 = 0; k0 < G; k0 += BK) {
        int r = bm + ar, kk = k0 + ak;
        float4 xv = make_float4(0.f, 0.f, 0.f, 0.f);
        float4 hv4 = make_float4(0.f, 0.f, 0.f, 0.f);
        if (r < M && kk < G) {
            xv = *(const float4*)&X[(size_t)r * G + kk];
            xv.x = eluf(xv.x); xv.y = eluf(xv.y);
            xv.z = eluf(xv.z); xv.w = eluf(xv.w);
            hv4 = *(const float4*)&H[(size_t)r * G + kk];
        }
        Ax[ak + 0][ar] = xv.x;  Ax[ak + 1][ar] = xv.y;
        Ax[ak + 2][ar] = xv.z;  Ax[ak + 3][ar] = xv.w;
        Ah[ak + 0][ar] = hv4.x; Ah[ak + 1][ar] = hv4.y;
        Ah[ak + 2][ar] = hv4.z; Ah[ak + 3][ar] = hv4.w;

        int kw = k0 + bk, cc = bn + bc;
#pragma unroll
        for (int g = 0; g < 3; ++g) {
            float4 bxv = make_float4(0.f, 0.f, 0.f, 0.f);
            float4 bhv = make_float4(0.f, 0.f, 0.f, 0.f);
            if (kw < G && cc < G) {
                bxv = *(const float4*)&Wx[(size_t)kw * (3 * G) + g * G + cc];
                bhv = *(const float4*)&Wh[(size_t)kw * (3 * G) + g * G + cc];
            }
            *(float4*)&Bx[g][bk][bc] = bxv;
            *(float4*)&Bh[g][bk][bc] = bhv;
        }

        __syncthreads();
#pragma unroll
        for (int kk2 = 0; kk2 < BK; ++kk2) {
            float4 a4x = *(const float4*)&Ax[kk2][ty * 4];
            float4 a4h = *(const float4*)&Ah[kk2][ty * 4];
#pragma unroll
            for (int g = 0; g < 3; ++g) {
                float4 b4x = *(const float4*)&Bx[g][kk2][tx * 4];
                float4 b4h = *(const float4*)&Bh[g][kk2][tx * 4];
#define GFMA(acc, a4, b4)                                       \
                acc[g][0][0] = fmaf(a4.x, b4.x, acc[g][0][0]);  \
                acc[g][0][1] = fmaf(a4.x, b4.y, acc[g][0][1]);  \
                acc[g][0][2] = fmaf(a4.x, b4.z, acc[g][0][2]);  \
                acc[g][0][3] = fmaf(a4.x, b4.w, acc[g][0][3]);  \
                acc[g][1][0] = fmaf(a4.y, b4.x, acc[g][1][0]);  \
                acc[g][1][1] = fmaf(a4.y, b4.y, acc[g][1][1]);  \
                acc[g][1][2] = fmaf(a4.y, b4.z, acc[g][1][2]);  \
                acc[g][1][3] = fmaf(a4.y, b4.w, acc[g][1][3]);  \
                acc[g][2][0] = fmaf(a4.z, b4.x, acc[g][2][0]);  \
                acc[g][2][1] = fmaf(a4.z, b4.y, acc[g][2][1]);  \
                acc[g][2][2] = fmaf(a4.z, b4.z, acc[g][2][2]);  \
                acc[g][2][3] = fmaf(a4.z, b4.w, acc[g][2][3]);  \
                acc[g][3][0] = fmaf(a4.w, b4.x, acc[g][3][0]);  \
                acc[g][3][1] = fmaf(a4.w, b4.y, acc[g][3][1]);  \
                acc[g][3][2] = fmaf(a4.w, b4.z, acc[g][3][2]);  \
                acc[g][3][3] = fmaf(a4.w, b4.w, acc[g][3][3]);
                GFMA(accx, a4x, b4x)
                GFMA(acch, a4h, b4h)
#undef GFMA
            }
        }
        __syncthreads();
    }

#pragma unroll
    for (int i = 0; i < 4; ++i) {
        int r = bm + ty * 4 + i;
        if (r >= M) continue;
#pragma unroll
        for (int j = 0; j < 4; ++j) {
            int c = bn + tx * 4 + j;
            if (c >= G) continue;
            float rg = sigm(accx[0][i][j] + bx[c] + acch[0][i][j] + bh[c]);
            float zg = sigm(accx[1][i][j] + bx[c + G] + acch[1][i][j] + bh[c + G]);
            float ng = tanhf(accx[2][i][j] + bx[c + 2 * G] +
                             rg * (acch[2][i][j] + bh[c + 2 * G]));
            float hprev = H[(size_t)r * G + c];
            float o = (1.f - zg) * ng + zg * hprev;
            OUT[(size_t)r * G + c] = fmaxf(o, 0.f);
        }
    }
}

// ------------- layer-2 logits -------------
__global__ __launch_bounds__(256) void logits2_k(
    const float* __restrict__ h0,
    const float* __restrict__ W, const float* __restrict__ b,
    const int* __restrict__ src, const int* __restrict__ dst,
    float* __restrict__ lg, float* __restrict__ sden, int E)
{
    int wid = blockIdx.x * 4 + (threadIdx.x >> 6);
    int lane = threadIdx.x & 63;
    if (wid >= E) return;
    int d = dst[wid], s_ = src[wid];
    float sum = 0.f;
    for (int j = lane; j < G; j += 64)
        sum += h0[(size_t)d * G + j] * W[j] + h0[(size_t)s_ * G + j] * W[G + j];
    for (int off = 32; off; off >>= 1) sum += __shfl_down(sum, off);
    if (lane == 0) {
        float l = leakyf(sum + b[0]);
        lg[wid] = l;
        atomicAdd(&sden[d], expf(l));
    }
}

// ------------- c2[dst] += hvp[src] * (exp(lg)/sden[dst] + 1) -------------
__global__ __launch_bounds__(256) void c2_k(
    const float* __restrict__ hvp,
    const float* __restrict__ lg, const float* __restrict__ sden,
    const int* __restrict__ src, const int* __restrict__ dst,
    float* __restrict__ cacc, int E)
{
    int wid = blockIdx.x * 4 + (threadIdx.x >> 6);
    int lane = threadIdx.x & 63;
    if (wid >= E) return;
    int d = dst[wid], s_ = src[wid];
    float a2 = expf(lg[wid]) / sden[d] + 1.0f;
    for (int j = lane; j < G; j += 64)
        atomicAdd(&cacc[(size_t)d * G + j], hvp[(size_t)s_ * G + j] * a2);
}

// ------------- batchnorm stats -------------
__global__ __launch_bounds__(256) void bnstat_k(
    const float* __restrict__ h1, float* __restrict__ stats, long total)
{
    __shared__ float ls[2 * G];
    for (int t = threadIdx.x; t < 2 * G; t += 256) ls[t] = 0.f;
    __syncthreads();
    for (long idx = (long)blockIdx.x * 256 + threadIdx.x; idx < total;
         idx += (long)gridDim.x * 256) {
        float v = h1[idx];
        int c = (int)(idx % G);
        atomicAdd(&ls[c], v);
        atomicAdd(&ls[G + c], v * v);
    }
    __syncthreads();
    for (int t = threadIdx.x; t < 2 * G; t += 256) atomicAdd(&stats[t], ls[t]);
}

// ------------- out = h0(=in d_out) + bn(h1), in place -------------
__global__ __launch_bounds__(256) void final_k(
    float* __restrict__ out, const float* __restrict__ h1,
    const float* __restrict__ stats,
    const float* __restrict__ g, const float* __restrict__ bb, int Nn)
{
    long total = (long)Nn * G;
    for (long idx = (long)blockIdx.x * 256 + threadIdx.x; idx < total;
         idx += (long)gridDim.x * 256) {
        int c = (int)(idx % G);
        float mu  = stats[c] / Nn;
        float var = stats[G + c] / Nn - mu * mu;
        float xh  = (h1[idx] - mu) * rsqrtf(var + 1e-5f);
        out[idx] = out[idx] + g[c] * xh + bb[c];
    }
}

extern "C" void kernel_launch(void* const* d_in, const int* in_sizes, int n_in,
                              void* d_out, int out_size, void* d_ws, size_t ws_size,
                              hipStream_t stream)
{
    const float* node_feats = (const float*)d_in[0];
    const float* edge_feats = (const float*)d_in[1];
    const float* gc_node_W  = (const float*)d_in[2];
    const float* gc_node_b  = (const float*)d_in[3];
    const float* gc_e1_W    = (const float*)d_in[4];
    const float* gc_e1_b    = (const float*)d_in[5];
    const float* gc_e2_W    = (const float*)d_in[6];
    const float* gc_e2_b    = (const float*)d_in[7];
    const float* gc_et_W    = (const float*)d_in[8];
    const float* gc_et_b    = (const float*)d_in[9];
    const float* gc_gru_Wx  = (const float*)d_in[10];
    const float* gc_gru_Wh  = (const float*)d_in[11];
    const float* gc_gru_bx  = (const float*)d_in[12];
    const float* gc_gru_bh  = (const float*)d_in[13];
    const float* l1_e_W     = (const float*)d_in[14];
    const float* l1_e_b     = (const float*)d_in[15];
    const float* l1_pn_W    = (const float*)d_in[16];
    const float* l1_pn_b    = (const float*)d_in[17];
    const float* l1_gru_Wx  = (const float*)d_in[18];
    const float* l1_gru_Wh  = (const float*)d_in[19];
    const float* l1_gru_bx  = (const float*)d_in[20];
    const float* l1_gru_bh  = (const float*)d_in[21];
    const float* l1_bn_g    = (const float*)d_in[22];
    const float* l1_bn_b    = (const float*)d_in[23];
    const int*   src        = (const int*)d_in[24];
    const int*   dst        = (const int*)d_in[25];

    const int Nn = in_sizes[0] / NF;
    const int E  = in_sizes[24];

    float* ws = (float*)d_ws;
    size_t o = 0;
    float* hv    = ws + o; o += (size_t)Nn * G;   // hv_new -> hvp -> h1
    float* cbuf  = ws + o; o += (size_t)Nn * G;   // c -> c2
    float* lg    = ws + o; o += (size_t)E;
    float* sden  = ws + o; o += (size_t)Nn;
    float* hd    = ws + o; o += (size_t)Nn;
    float* stats = ws + o; o += 512;
    // total ~20.5M floats = 82 MB

    float* h0  = (float*)d_out;   // h0 lives in the output buffer
    float* hvp = hv;              // reuse after GRU1 (hv dead after grufuse#1)
    float* h1  = hv;              // reuse after c2_k (hvp dead; NOT cbuf — that
                                  // aliased grufuse#2's X input and raced)

    dim3 blk(16, 16);
    const int gN = (Nn + BM - 1) / BM;
    const int gE = (E + BM - 1) / BM;
    const int eWaves = (E + 3) / 4;
    const int nWaves = (Nn + 3) / 4;
    const long totNG = (long)Nn * G;

    // ---------- GetContext ----------
    hipMemsetAsync(sden, 0, (size_t)Nn * sizeof(float), stream);
    hipMemsetAsync(cbuf, 0, (size_t)Nn * G * sizeof(float), stream);
    hipMemsetAsync(stats, 0, 512 * sizeof(float), stream);

    // hv = leaky(node @ ncW + b)
    gemm_k<E_LEAKY><<<dim3(gN, 4), blk, 0, stream>>>(
        node_feats, gc_node_W, gc_node_b, hv, Nn, NF, G);

    // hd[n] = hv[n] . e2W[0:200]
    hd_k<<<nWaves, 256, 0, stream>>>(hv, gc_e2_W, hd, Nn);

    // logits + softmax denom (recomputes he1)
    edgeA_k<<<gE, blk, 0, stream>>>(node_feats, edge_feats, src, dst,
                                    gc_e1_W, gc_e1_b, gc_e2_W, gc_e2_b,
                                    hd, lg, sden, E);

    // c[dst] += a * (he1 @ etW + etb)   (recomputes he1)
    edgeB_k<<<gE, blk, 0, stream>>>(node_feats, edge_feats, src, dst,
                                    gc_e1_W, gc_e1_b, gc_et_W, gc_et_b,
                                    lg, sden, cbuf, E);

    // h0 = relu(GRU(elu(c), hv))
    grufuse_k<<<dim3(gN, 4), blk, 0, stream>>>(
        cbuf, hv, gc_gru_Wx, gc_gru_Wh, gc_gru_bx, gc_gru_bh, h0, Nn);

    // ---------- GNNLayer ----------
    hipMemsetAsync(sden, 0, (size_t)Nn * sizeof(float), stream);

    logits2_k<<<eWaves, 256, 0, stream>>>(h0, l1_e_W, l1_e_b, src, dst, lg, sden, E);

    // hvp = h0 @ pnW + b   (overwrites hv — dead after grufuse#1)
    gemm_k<E_BIAS><<<dim3(gN, 4), blk, 0, stream>>>(
        h0, l1_pn_W, l1_pn_b, hvp, Nn, G, G);

    hipMemsetAsync(cbuf, 0, (size_t)Nn * G * sizeof(float), stream);

    // c2[dst] += hvp[src] * (softmax + 1)
    c2_k<<<eWaves, 256, 0, stream>>>(hvp, lg, sden, src, dst, cbuf, E);

    // h1 = relu(GRU(elu(c2), h0))  — OUT=hv, no alias with X=cbuf or H=h0
    grufuse_k<<<dim3(gN, 4), blk, 0, stream>>>(
        cbuf, h0, l1_gru_Wx, l1_gru_Wh, l1_gru_bx, l1_gru_bh, h1, Nn);

    // BatchNorm + residual
    bnstat_k<<<2048, 256, 0, stream>>>(h1, stats, totNG);
    final_k<<<2048, 256, 0, stream>>>((float*)d_out, h1, stats,
                                      l1_bn_g, l1_bn_b, Nn);
}

// Round 4
// 2280.651 us; speedup vs baseline: 1.9749x; 1.9749x over previous
//
#include <hip/hip_runtime.h>
#include <math.h>

#define G 200
#define NF 128
#define EF 64

constexpr int BM = 64, BN = 64, BK = 16;

enum { E_LEAKY = 0, E_BIAS = 1 };

typedef __attribute__((ext_vector_type(8))) short bf16x8;
typedef __attribute__((ext_vector_type(4))) float f32x4;

__device__ __forceinline__ float leakyf(float x) { return x > 0.f ? x : 0.01f * x; }
__device__ __forceinline__ float eluf(float x)   { return x > 0.f ? x : (expf(x) - 1.f); }
__device__ __forceinline__ float sigm(float x)   { return 1.f / (1.f + expf(-x)); }

__device__ __forceinline__ unsigned short f2bf(float x) {
    union { float f; unsigned int u; } v; v.f = x;
    unsigned int r = v.u + 0x7FFF + ((v.u >> 16) & 1);   // RNE
    return (unsigned short)(r >> 16);
}
__device__ __forceinline__ unsigned int pk2(float a, float b) {
    return (unsigned int)f2bf(a) | ((unsigned int)f2bf(b) << 16);
}

// ---------------- generic tiled f32 GEMM (dense A) ----------------
template <int EPI>
__global__ __launch_bounds__(256) void gemm_k(
    const float* __restrict__ A, const float* __restrict__ W,
    const float* __restrict__ bias, float* __restrict__ C,
    int M, int K, int Ncol)
{
    __shared__ float As[BK][BM];
    __shared__ float Bs[BK][BN];
    const int bm = blockIdx.x * BM;
    const int bn = blockIdx.y * BN;
    const int tx = threadIdx.x, ty = threadIdx.y;
    const int tid = ty * 16 + tx;
    const int ar = tid >> 2, ak = (tid & 3) * 4;
    const int bk = tid >> 4, bc = (tid & 15) * 4;

    float acc[4][4] = {};

    for (int k0 = 0; k0 < K; k0 += BK) {
        float4 av = make_float4(0.f, 0.f, 0.f, 0.f);
        int r = bm + ar, kk = k0 + ak;
        if (r < M && kk < K) av = *(const float4*)&A[(size_t)r * K + kk];
        As[ak + 0][ar] = av.x; As[ak + 1][ar] = av.y;
        As[ak + 2][ar] = av.z; As[ak + 3][ar] = av.w;

        float4 bv = make_float4(0.f, 0.f, 0.f, 0.f);
        int kb = k0 + bk, cb = bn + bc;
        if (kb < K && cb < Ncol) bv = *(const float4*)&W[(size_t)kb * Ncol + cb];
        *(float4*)&Bs[bk][bc] = bv;

        __syncthreads();
#pragma unroll
        for (int kk2 = 0; kk2 < BK; ++kk2) {
            float4 a4 = *(const float4*)&As[kk2][ty * 4];
            float4 b4 = *(const float4*)&Bs[kk2][tx * 4];
#define FMA4(i, ax)                                  \
            acc[i][0] = fmaf(ax, b4.x, acc[i][0]);   \
            acc[i][1] = fmaf(ax, b4.y, acc[i][1]);   \
            acc[i][2] = fmaf(ax, b4.z, acc[i][2]);   \
            acc[i][3] = fmaf(ax, b4.w, acc[i][3]);
            FMA4(0, a4.x) FMA4(1, a4.y) FMA4(2, a4.z) FMA4(3, a4.w)
#undef FMA4
        }
        __syncthreads();
    }

#pragma unroll
    for (int i = 0; i < 4; ++i) {
        int r = bm + ty * 4 + i;
        if (r >= M) continue;
#pragma unroll
        for (int j = 0; j < 4; ++j) {
            int cc = bn + tx * 4 + j;
            if (cc >= Ncol) continue;
            float v = acc[i][j] + bias[cc];
            C[(size_t)r * Ncol + cc] = (EPI == E_LEAKY) ? leakyf(v) : v;
        }
    }
}

// ---------------- hd[n] = hv[n,:] . e2W[0:200] ----------------
__global__ __launch_bounds__(256) void hd_k(
    const float* __restrict__ hv, const float* __restrict__ e2W,
    float* __restrict__ hd, int Nn)
{
    int wid = blockIdx.x * 4 + (threadIdx.x >> 6);
    int lane = threadIdx.x & 63;
    if (wid >= Nn) return;
    float s = 0.f;
    for (int j = lane; j < G; j += 64) s += hv[(size_t)wid * G + j] * e2W[j];
    for (int off = 32; off; off >>= 1) s += __shfl_down(s, off);
    if (lane == 0) hd[wid] = s;
}

// -------- weight prep: W1t[n][k] = bf16(W1[k][n]); etWt[n][k] = bf16(etW[k][n]) --------
// W1t: [208][192] (n>=200 -> 0). etWt: [208][224] (n>=200 or k>=200 -> 0)
__global__ __launch_bounds__(256) void wprep_k(
    const float* __restrict__ W1, const float* __restrict__ etW,
    unsigned short* __restrict__ W1t, unsigned short* __restrict__ etWt)
{
    const int n1 = 208 * 192, n2 = 208 * 224;
    for (int i = blockIdx.x * 256 + threadIdx.x; i < n1; i += gridDim.x * 256) {
        int n = i / 192, k = i % 192;
        W1t[i] = (n < 200) ? f2bf(W1[(size_t)k * 200 + n]) : 0;
    }
    for (int i = blockIdx.x * 256 + threadIdx.x; i < n2; i += gridDim.x * 256) {
        int n = i / 224, k = i % 224;
        etWt[i] = (n < 200 && k < 200) ? f2bf(etW[(size_t)k * 200 + n]) : 0;
    }
}

// ============ fused edge kernel (MFMA bf16) ============
// he1 = leaky(concat(node[src],edge) @ W1 + b1)          [64 x 200 per block]
// lg  = leaky(he1 . e2W[200:] + hd[dst] + e2b);  sden[dst] += exp(lg)
// cacc[dst] += exp(lg) * (he1 @ etW + etb)   (normalized by sden later)
__global__ __launch_bounds__(256) void edgefuse_k(
    const float* __restrict__ node, const float* __restrict__ edgef,
    const int* __restrict__ src, const int* __restrict__ dst,
    const unsigned short* __restrict__ W1t, const float* __restrict__ b1,
    const unsigned short* __restrict__ etWt, const float* __restrict__ etb,
    const float* __restrict__ e2W, const float* __restrict__ e2b,
    const float* __restrict__ hd,
    float* __restrict__ sden, float* __restrict__ cacc, int E)
{
    // U: union of A [64][200] bf16 (cols 0..191 used) and he1s [64][232] bf16
    __shared__ __align__(16) unsigned short U[64 * 232];
    __shared__ __align__(16) unsigned short Wt[208 * 40];   // staged B chunk [208][k:32] pad 40
    __shared__ float rowlg[64];
    __shared__ float pexp_s[64];
    __shared__ int   dst_s[64];

    const int tid  = threadIdx.x;
    const int w    = tid >> 6;          // wave 0..3 -> rows 16w..16w+15
    const int lane = tid & 63;
    const int l15  = lane & 15;
    const int lq   = lane >> 4;         // 0..3
    const int eb   = blockIdx.x * 64;

    // ---- stage A = concat(node[src], edge) as bf16 into U[64][200] ----
    {
        const int r4 = tid >> 2, q = tid & 3;   // 4 threads per row
        const int e  = eb + r4;
        if (e < E) {
            const int se = src[e];
            const float4* np = (const float4*)(node + (size_t)se * NF);
            const float4* ep = (const float4*)(edgef + (size_t)e * EF);
            uint4* rowp = (uint4*)(U + r4 * 200);
#pragma unroll
            for (int i = 0; i < 4; ++i) {       // node: 128 f32 -> 16 uint4
                float4 a = np[q * 8 + 2 * i];
                float4 b = np[q * 8 + 2 * i + 1];
                uint4 u; u.x = pk2(a.x, a.y); u.y = pk2(a.z, a.w);
                u.z = pk2(b.x, b.y); u.w = pk2(b.z, b.w);
                rowp[q * 4 + i] = u;
            }
            uint4* edp = (uint4*)(U + r4 * 200 + 128);
#pragma unroll
            for (int i = 0; i < 2; ++i) {       // edge: 64 f32 -> 8 uint4
                float4 a = ep[q * 4 + 2 * i];
                float4 b = ep[q * 4 + 2 * i + 1];
                uint4 u; u.x = pk2(a.x, a.y); u.y = pk2(a.z, a.w);
                u.z = pk2(b.x, b.y); u.w = pk2(b.z, b.w);
                edp[q * 2 + i] = u;
            }
        } else {
            uint4 z = make_uint4(0, 0, 0, 0);
            uint4* rowp = (uint4*)(U + r4 * 200);
#pragma unroll
            for (int i = 0; i < 4; ++i) rowp[q * 4 + i] = z;
            uint4* edp = (uint4*)(U + r4 * 200 + 128);
            edp[q * 2] = z; edp[q * 2 + 1] = z;
        }
        if (tid < 64) dst_s[tid] = (eb + tid < E) ? dst[eb + tid] : 0;
    }
    __syncthreads();

    // ---- he1: A[64][192] @ W1[192][200] via 16x16x32 MFMA ----
    f32x4 acc[13];
#pragma unroll
    for (int t = 0; t < 13; ++t) acc[t] = (f32x4){0.f, 0.f, 0.f, 0.f};

    for (int c = 0; c < 6; ++c) {
        for (int q = tid; q < 832; q += 256) {          // 208 rows x 4 uint4
            int n = q >> 2, s = q & 3;
            *(uint4*)(Wt + n * 40 + s * 8) =
                *(const uint4*)(W1t + (size_t)n * 192 + c * 32 + s * 8);
        }
        __syncthreads();
        bf16x8 a = *(const bf16x8*)(U + (w * 16 + l15) * 200 + c * 32 + lq * 8);
#pragma unroll
        for (int t = 0; t < 13; ++t) {
            bf16x8 b = *(const bf16x8*)(Wt + (t * 16 + l15) * 40 + lq * 8);
            acc[t] = __builtin_amdgcn_mfma_f32_16x16x32_bf16(a, b, acc[t], 0, 0, 0);
        }
        __syncthreads();
    }

    // ---- epilogue: leaky+bias -> he1s (bf16, U as [64][232]); logit partials ----
    float p[4] = {0.f, 0.f, 0.f, 0.f};
#pragma unroll
    for (int t = 0; t < 13; ++t) {
        const int col = t * 16 + l15;
#pragma unroll
        for (int r = 0; r < 4; ++r) {
            const int row = w * 16 + lq * 4 + r;
            float v = 0.f;
            if (col < 200) {
                v = leakyf(acc[t][r] + b1[col]);
                p[r] = fmaf(v, e2W[200 + col], p[r]);
            }
            U[row * 232 + col] = f2bf(v);
        }
    }
    // zero pad cols 208..223 (read by last et K-chunk)
    if (tid < 128)
        *(uint4*)(U + (tid >> 1) * 232 + 208 + (tid & 1) * 8) = make_uint4(0, 0, 0, 0);

    // reduce logit partials over the 16 lanes (cols) of each quarter
#pragma unroll
    for (int r = 0; r < 4; ++r) {
        p[r] += __shfl_xor(p[r], 1);
        p[r] += __shfl_xor(p[r], 2);
        p[r] += __shfl_xor(p[r], 4);
        p[r] += __shfl_xor(p[r], 8);
    }
    if (l15 == 0) {
#pragma unroll
        for (int r = 0; r < 4; ++r) rowlg[w * 16 + lq * 4 + r] = p[r];
    }
    __syncthreads();

    if (tid < 64) {
        const int e = eb + tid;
        float pe = 0.f;
        if (e < E) {
            float l = leakyf(rowlg[tid] + hd[dst_s[tid]] + e2b[0]);
            pe = expf(l);
            atomicAdd(&sden[dst_s[tid]], pe);
        }
        pexp_s[tid] = pe;
    }
    __syncthreads();

    // ---- et: he1s[64][224] @ etW[200][200] via MFMA ----
    f32x4 acc2[13];
#pragma unroll
    for (int t = 0; t < 13; ++t) acc2[t] = (f32x4){0.f, 0.f, 0.f, 0.f};

    for (int c = 0; c < 7; ++c) {
        for (int q = tid; q < 832; q += 256) {
            int n = q >> 2, s = q & 3;
            *(uint4*)(Wt + n * 40 + s * 8) =
                *(const uint4*)(etWt + (size_t)n * 224 + c * 32 + s * 8);
        }
        __syncthreads();
        bf16x8 a = *(const bf16x8*)(U + (w * 16 + l15) * 232 + c * 32 + lq * 8);
#pragma unroll
        for (int t = 0; t < 13; ++t) {
            bf16x8 b = *(const bf16x8*)(Wt + (t * 16 + l15) * 40 + lq * 8);
            acc2[t] = __builtin_amdgcn_mfma_f32_16x16x32_bf16(a, b, acc2[t], 0, 0, 0);
        }
        __syncthreads();
    }

    // ---- scatter: cacc[dst[row]] += pexp[row] * (acc2 + etb) ----
#pragma unroll
    for (int r = 0; r < 4; ++r) {
        const int row = w * 16 + lq * 4 + r;
        const float pe = pexp_s[row];
        if (pe != 0.f) {
            float* base = cacc + (size_t)dst_s[row] * G;
#pragma unroll
            for (int t = 0; t < 13; ++t) {
                const int col = t * 16 + l15;
                if (col < 200)
                    atomicAdd(base + col, pe * (acc2[t][r] + etb[col]));
            }
        }
    }
}

// ------------- fused GRU: out = relu(GRU(elu(X / xdiv), H)) -------------
__global__ __launch_bounds__(256) void grufuse_k(
    const float* __restrict__ X, const float* __restrict__ H,
    const float* __restrict__ xdiv,
    const float* __restrict__ Wx, const float* __restrict__ Wh,
    const float* __restrict__ bx, const float* __restrict__ bh,
    float* __restrict__ OUT, int M)
{
    __shared__ float Ax[BK][BM];
    __shared__ float Ah[BK][BM];
    __shared__ float Bx[3][BK][BN];
    __shared__ float Bh[3][BK][BN];

    const int bm = blockIdx.x * BM;
    const int bn = blockIdx.y * BN;
    const int tx = threadIdx.x, ty = threadIdx.y;
    const int tid = ty * 16 + tx;
    const int ar = tid >> 2, ak = (tid & 3) * 4;
    const int bk = tid >> 4, bc = (tid & 15) * 4;

    float accx[3][4][4] = {};
    float acch[3][4][4] = {};

    for (int k0 = 0; k0 < G; k0 += BK) {
        int r = bm + ar, kk = k0 + ak;
        float4 xv = make_float4(0.f, 0.f, 0.f, 0.f);
        float4 hv4 = make_float4(0.f, 0.f, 0.f, 0.f);
        if (r < M && kk < G) {
            xv = *(const float4*)&X[(size_t)r * G + kk];
            if (xdiv) {
                float dv = xdiv[r];
                float inv = (dv > 0.f) ? 1.f / dv : 0.f;
                xv.x *= inv; xv.y *= inv; xv.z *= inv; xv.w *= inv;
            }
            xv.x = eluf(xv.x); xv.y = eluf(xv.y);
            xv.z = eluf(xv.z); xv.w = eluf(xv.w);
            hv4 = *(const float4*)&H[(size_t)r * G + kk];
        }
        Ax[ak + 0][ar] = xv.x;  Ax[ak + 1][ar] = xv.y;
        Ax[ak + 2][ar] = xv.z;  Ax[ak + 3][ar] = xv.w;
        Ah[ak + 0][ar] = hv4.x; Ah[ak + 1][ar] = hv4.y;
        Ah[ak + 2][ar] = hv4.z; Ah[ak + 3][ar] = hv4.w;

        int kw = k0 + bk, cc = bn + bc;
#pragma unroll
        for (int g = 0; g < 3; ++g) {
            float4 bxv = make_float4(0.f, 0.f, 0.f, 0.f);
            float4 bhv = make_float4(0.f, 0.f, 0.f, 0.f);
            if (kw < G && cc < G) {
                bxv = *(const float4*)&Wx[(size_t)kw * (3 * G) + g * G + cc];
                bhv = *(const float4*)&Wh[(size_t)kw * (3 * G) + g * G + cc];
            }
            *(float4*)&Bx[g][bk][bc] = bxv;
            *(float4*)&Bh[g][bk][bc] = bhv;
        }

        __syncthreads();
#pragma unroll
        for (int kk2 = 0; kk2 < BK; ++kk2) {
            float4 a4x = *(const float4*)&Ax[kk2][ty * 4];
            float4 a4h = *(const float4*)&Ah[kk2][ty * 4];
#pragma unroll
            for (int g = 0; g < 3; ++g) {
                float4 b4x = *(const float4*)&Bx[g][kk2][tx * 4];
                float4 b4h = *(const float4*)&Bh[g][kk2][tx * 4];
#define GFMA(acc, a4, b4)                                       \
                acc[g][0][0] = fmaf(a4.x, b4.x, acc[g][0][0]);  \
                acc[g][0][1] = fmaf(a4.x, b4.y, acc[g][0][1]);  \
                acc[g][0][2] = fmaf(a4.x, b4.z, acc[g][0][2]);  \
                acc[g][0][3] = fmaf(a4.x, b4.w, acc[g][0][3]);  \
                acc[g][1][0] = fmaf(a4.y, b4.x, acc[g][1][0]);  \
                acc[g][1][1] = fmaf(a4.y, b4.y, acc[g][1][1]);  \
                acc[g][1][2] = fmaf(a4.y, b4.z, acc[g][1][2]);  \
                acc[g][1][3] = fmaf(a4.y, b4.w, acc[g][1][3]);  \
                acc[g][2][0] = fmaf(a4.z, b4.x, acc[g][2][0]);  \
                acc[g][2][1] = fmaf(a4.z, b4.y, acc[g][2][1]);  \
                acc[g][2][2] = fmaf(a4.z, b4.z, acc[g][2][2]);  \
                acc[g][2][3] = fmaf(a4.z, b4.w, acc[g][2][3]);  \
                acc[g][3][0] = fmaf(a4.w, b4.x, acc[g][3][0]);  \
                acc[g][3][1] = fmaf(a4.w, b4.y, acc[g][3][1]);  \
                acc[g][3][2] = fmaf(a4.w, b4.z, acc[g][3][2]);  \
                acc[g][3][3] = fmaf(a4.w, b4.w, acc[g][3][3]);
                GFMA(accx, a4x, b4x)
                GFMA(acch, a4h, b4h)
#undef GFMA
            }
        }
        __syncthreads();
    }

#pragma unroll
    for (int i = 0; i < 4; ++i) {
        int r = bm + ty * 4 + i;
        if (r >= M) continue;
#pragma unroll
        for (int j = 0; j < 4; ++j) {
            int c = bn + tx * 4 + j;
            if (c >= G) continue;
            float rg = sigm(accx[0][i][j] + bx[c] + acch[0][i][j] + bh[c]);
            float zg = sigm(accx[1][i][j] + bx[c + G] + acch[1][i][j] + bh[c + G]);
            float ng = tanhf(accx[2][i][j] + bx[c + 2 * G] +
                             rg * (acch[2][i][j] + bh[c + 2 * G]));
            float hprev = H[(size_t)r * G + c];
            float o = (1.f - zg) * ng + zg * hprev;
            OUT[(size_t)r * G + c] = fmaxf(o, 0.f);
        }
    }
}

// ------------- layer-2 logits -------------
__global__ __launch_bounds__(256) void logits2_k(
    const float* __restrict__ h0,
    const float* __restrict__ W, const float* __restrict__ b,
    const int* __restrict__ src, const int* __restrict__ dst,
    float* __restrict__ lg, float* __restrict__ sden, int E)
{
    int wid = blockIdx.x * 4 + (threadIdx.x >> 6);
    int lane = threadIdx.x & 63;
    if (wid >= E) return;
    int d = dst[wid], s_ = src[wid];
    float sum = 0.f;
    for (int j = lane; j < G; j += 64)
        sum += h0[(size_t)d * G + j] * W[j] + h0[(size_t)s_ * G + j] * W[G + j];
    for (int off = 32; off; off >>= 1) sum += __shfl_down(sum, off);
    if (lane == 0) {
        float l = leakyf(sum + b[0]);
        lg[wid] = l;
        atomicAdd(&sden[d], expf(l));
    }
}

// ------------- c2[dst] += hvp[src] * (exp(lg)/sden[dst] + 1) -------------
__global__ __launch_bounds__(256) void c2_k(
    const float* __restrict__ hvp,
    const float* __restrict__ lg, const float* __restrict__ sden,
    const int* __restrict__ src, const int* __restrict__ dst,
    float* __restrict__ cacc, int E)
{
    int wid = blockIdx.x * 4 + (threadIdx.x >> 6);
    int lane = threadIdx.x & 63;
    if (wid >= E) return;
    int d = dst[wid], s_ = src[wid];
    float a2 = expf(lg[wid]) / sden[d] + 1.0f;
    for (int j = lane; j < G; j += 64)
        atomicAdd(&cacc[(size_t)d * G + j], hvp[(size_t)s_ * G + j] * a2);
}

// ------------- batchnorm stats -------------
__global__ __launch_bounds__(256) void bnstat_k(
    const float* __restrict__ h1, float* __restrict__ stats, long total)
{
    __shared__ float ls[2 * G];
    for (int t = threadIdx.x; t < 2 * G; t += 256) ls[t] = 0.f;
    __syncthreads();
    for (long idx = (long)blockIdx.x * 256 + threadIdx.x; idx < total;
         idx += (long)gridDim.x * 256) {
        float v = h1[idx];
        int c = (int)(idx % G);
        atomicAdd(&ls[c], v);
        atomicAdd(&ls[G + c], v * v);
    }
    __syncthreads();
    for (int t = threadIdx.x; t < 2 * G; t += 256) atomicAdd(&stats[t], ls[t]);
}

// ------------- out = h0(=in d_out) + bn(h1), in place -------------
__global__ __launch_bounds__(256) void final_k(
    float* __restrict__ out, const float* __restrict__ h1,
    const float* __restrict__ stats,
    const float* __restrict__ g, const float* __restrict__ bb, int Nn)
{
    long total = (long)Nn * G;
    for (long idx = (long)blockIdx.x * 256 + threadIdx.x; idx < total;
         idx += (long)gridDim.x * 256) {
        int c = (int)(idx % G);
        float mu  = stats[c] / Nn;
        float var = stats[G + c] / Nn - mu * mu;
        float xh  = (h1[idx] - mu) * rsqrtf(var + 1e-5f);
        out[idx] = out[idx] + g[c] * xh + bb[c];
    }
}

extern "C" void kernel_launch(void* const* d_in, const int* in_sizes, int n_in,
                              void* d_out, int out_size, void* d_ws, size_t ws_size,
                              hipStream_t stream)
{
    const float* node_feats = (const float*)d_in[0];
    const float* edge_feats = (const float*)d_in[1];
    const float* gc_node_W  = (const float*)d_in[2];
    const float* gc_node_b  = (const float*)d_in[3];
    const float* gc_e1_W    = (const float*)d_in[4];
    const float* gc_e1_b    = (const float*)d_in[5];
    const float* gc_e2_W    = (const float*)d_in[6];
    const float* gc_e2_b    = (const float*)d_in[7];
    const float* gc_et_W    = (const float*)d_in[8];
    const float* gc_et_b    = (const float*)d_in[9];
    const float* gc_gru_Wx  = (const float*)d_in[10];
    const float* gc_gru_Wh  = (const float*)d_in[11];
    const float* gc_gru_bx  = (const float*)d_in[12];
    const float* gc_gru_bh  = (const float*)d_in[13];
    const float* l1_e_W     = (const float*)d_in[14];
    const float* l1_e_b     = (const float*)d_in[15];
    const float* l1_pn_W    = (const float*)d_in[16];
    const float* l1_pn_b    = (const float*)d_in[17];
    const float* l1_gru_Wx  = (const float*)d_in[18];
    const float* l1_gru_Wh  = (const float*)d_in[19];
    const float* l1_gru_bx  = (const float*)d_in[20];
    const float* l1_gru_bh  = (const float*)d_in[21];
    const float* l1_bn_g    = (const float*)d_in[22];
    const float* l1_bn_b    = (const float*)d_in[23];
    const int*   src        = (const int*)d_in[24];
    const int*   dst        = (const int*)d_in[25];

    const int Nn = in_sizes[0] / NF;
    const int E  = in_sizes[24];

    float* ws = (float*)d_ws;
    size_t o = 0;
    float* hv    = ws + o; o += (size_t)Nn * G;   // hv_new -> hvp -> h1
    float* cbuf  = ws + o; o += (size_t)Nn * G;   // cacc(layer1) -> c2
    float* lg    = ws + o; o += (size_t)E;        // layer-2 logits
    float* sden  = ws + o; o += (size_t)Nn;
    float* hd    = ws + o; o += (size_t)Nn;
    float* stats = ws + o; o += 512;
    unsigned short* W1t_g  = (unsigned short*)(ws + o); o += (208 * 192) / 2;
    unsigned short* etWt_g = (unsigned short*)(ws + o); o += (208 * 224) / 2;
    // total ~20.55M floats = 82.2 MB (round-3-proven size)

    float* h0  = (float*)d_out;
    float* hvp = hv;
    float* h1  = hv;

    dim3 blk(16, 16);
    const int gN = (Nn + BM - 1) / BM;
    const int gE = (E + 63) / 64;
    const int eWaves = (E + 3) / 4;
    const int nWaves = (Nn + 3) / 4;
    const long totNG = (long)Nn * G;

    // ---------- GetContext ----------
    hipMemsetAsync(sden, 0, (size_t)Nn * sizeof(float), stream);
    hipMemsetAsync(cbuf, 0, (size_t)Nn * G * sizeof(float), stream);
    hipMemsetAsync(stats, 0, 512 * sizeof(float), stream);

    wprep_k<<<256, 256, 0, stream>>>(gc_e1_W, gc_et_W, W1t_g, etWt_g);

    // hv = leaky(node @ ncW + b)
    gemm_k<E_LEAKY><<<dim3(gN, 4), blk, 0, stream>>>(
        node_feats, gc_node_W, gc_node_b, hv, Nn, NF, G);

    // hd[n] = hv[n] . e2W[0:200]
    hd_k<<<nWaves, 256, 0, stream>>>(hv, gc_e2_W, hd, Nn);

    // fused: he1 (MFMA) -> logits -> sden; exp*(he1@etW+etb) -> cbuf (unnormalized)
    edgefuse_k<<<gE, 256, 0, stream>>>(
        node_feats, edge_feats, src, dst,
        W1t_g, gc_e1_b, etWt_g, gc_et_b,
        gc_e2_W, gc_e2_b, hd, sden, cbuf, E);

    // h0 = relu(GRU(elu(cbuf / sden), hv))   (softmax normalization folded in)
    grufuse_k<<<dim3(gN, 4), blk, 0, stream>>>(
        cbuf, hv, sden, gc_gru_Wx, gc_gru_Wh, gc_gru_bx, gc_gru_bh, h0, Nn);

    // ---------- GNNLayer ----------
    hipMemsetAsync(sden, 0, (size_t)Nn * sizeof(float), stream);

    logits2_k<<<eWaves, 256, 0, stream>>>(h0, l1_e_W, l1_e_b, src, dst, lg, sden, E);

    // hvp = h0 @ pnW + b   (overwrites hv — dead after grufuse#1)
    gemm_k<E_BIAS><<<dim3(gN, 4), blk, 0, stream>>>(
        h0, l1_pn_W, l1_pn_b, hvp, Nn, G, G);

    hipMemsetAsync(cbuf, 0, (size_t)Nn * G * sizeof(float), stream);

    // c2[dst] += hvp[src] * (softmax + 1)
    c2_k<<<eWaves, 256, 0, stream>>>(hvp, lg, sden, src, dst, cbuf, E);

    // h1 = relu(GRU(elu(c2), h0))  — OUT=hv, no alias with X=cbuf or H=h0
    grufuse_k<<<dim3(gN, 4), blk, 0, stream>>>(
        cbuf, h0, nullptr, l1_gru_Wx, l1_gru_Wh, l1_gru_bx, l1_gru_bh, h1, Nn);

    // BatchNorm + residual
    bnstat_k<<<2048, 256, 0, stream>>>(h1, stats, totNG);
    final_k<<<2048, 256, 0, stream>>>((float*)d_out, h1, stats,
                                      l1_bn_g, l1_bn_b, Nn);
}

// Round 5
// 1934.922 us; speedup vs baseline: 2.3277x; 1.1787x over previous
//
#include <hip/hip_runtime.h>
#include <math.h>

#define G 200
#define NF 128
#define EF 64

typedef __attribute__((ext_vector_type(8))) short bf16x8;
typedef __attribute__((ext_vector_type(4))) float f32x4;

__device__ __forceinline__ float leakyf(float x) { return x > 0.f ? x : 0.01f * x; }
__device__ __forceinline__ float eluf(float x)   { return x > 0.f ? x : (expf(x) - 1.f); }
__device__ __forceinline__ float sigm(float x)   { return 1.f / (1.f + expf(-x)); }

__device__ __forceinline__ unsigned short f2bf(float x) {
    union { float f; unsigned int u; } v; v.f = x;
    unsigned int r = v.u + 0x7FFF + ((v.u >> 16) & 1);   // RNE
    return (unsigned short)(r >> 16);
}
__device__ __forceinline__ float bf2f(unsigned short u) {
    union { unsigned int i; float f; } v; v.i = ((unsigned int)u) << 16;
    return v.f;
}
__device__ __forceinline__ unsigned int pk2(float a, float b) {
    return (unsigned int)f2bf(a) | ((unsigned int)f2bf(b) << 16);
}

// ---------- generic weight transpose+bf16 prep: Wt[208][kpad] = W[k][n] ----------
__global__ __launch_bounds__(256) void tprep_k(
    const float* __restrict__ W, unsigned short* __restrict__ Wt,
    int Kreal, int kpad, int Nstride, int Nreal)
{
    int total = 208 * kpad;
    for (int i = blockIdx.x * 256 + threadIdx.x; i < total; i += gridDim.x * 256) {
        int n = i / kpad, k = i % kpad;
        Wt[i] = (n < Nreal && k < Kreal) ? f2bf(W[(size_t)k * Nstride + n]) : 0;
    }
}

// ---------- GRU weight prep ----------
// Wrzt[416][416]: n<208 -> r gate, n>=208 -> z gate; k<208 -> Wx rows, k>=208 -> Wh rows
// Wxnt/Whnt[208][224]: n-gate columns (400..599) transposed
__global__ __launch_bounds__(256) void wprep2_k(
    const float* __restrict__ Wx, const float* __restrict__ Wh,
    unsigned short* __restrict__ Wrzt,
    unsigned short* __restrict__ Wxnt, unsigned short* __restrict__ Whnt)
{
    const int t1 = 416 * 416;
    for (int i = blockIdx.x * 256 + threadIdx.x; i < t1; i += gridDim.x * 256) {
        int n = i / 416, k = i % 416;
        int gg = (n >= 208) ? 1 : 0;
        int cc = n - gg * 208;
        float v = 0.f;
        if (cc < 200) {
            if (k < 200)                  v = Wx[(size_t)k * 600 + gg * 200 + cc];
            else if (k >= 208 && k < 408) v = Wh[(size_t)(k - 208) * 600 + gg * 200 + cc];
        }
        Wrzt[i] = f2bf(v);
    }
    const int t2 = 208 * 224;
    for (int i = blockIdx.x * 256 + threadIdx.x; i < t2; i += gridDim.x * 256) {
        int n = i / 224, k = i % 224;
        bool ok = (n < 200 && k < 200);
        Wxnt[i] = ok ? f2bf(Wx[(size_t)k * 600 + 400 + n]) : 0;
        Whnt[i] = ok ? f2bf(Wh[(size_t)k * 600 + 400 + n]) : 0;
    }
}

// ---------- dense MFMA GEMM: OUT[M,200] = epi(X[M,Kreal] @ W + bias) ----------
// Wt[208][kpad=kch*32] pre-transposed bf16. astr = LDS row stride (bf16 elems).
__global__ __launch_bounds__(256) void mgemm_k(
    const float* __restrict__ X, const unsigned short* __restrict__ Wt,
    const float* __restrict__ bias, float* __restrict__ OUT,
    int M, int Kreal, int kch, int astr, int leaky)
{
    __shared__ __align__(16) unsigned short A[64 * 232];
    const int tid = threadIdx.x;
    const int w = tid >> 6, lane = tid & 63, l15 = lane & 15, lq = lane >> 4;
    const int bm = blockIdx.x * 64;
    const int kpad = kch * 32;
    const int nch8 = Kreal >> 3;

    for (int i = tid; i < 64 * nch8; i += 256) {
        int r = i / nch8, ch = i % nch8;
        int grow = bm + r;
        uint4 u = make_uint4(0, 0, 0, 0);
        if (grow < M) {
            const float4* xp = (const float4*)(X + (size_t)grow * Kreal + ch * 8);
            float4 a = xp[0], b = xp[1];
            u.x = pk2(a.x, a.y); u.y = pk2(a.z, a.w);
            u.z = pk2(b.x, b.y); u.w = pk2(b.z, b.w);
        }
        *(uint4*)&A[r * astr + ch * 8] = u;
    }
    // zero k-pad cols Kreal..kpad
    if (tid < 64) {
        for (int p = Kreal; p < kpad; p += 8)
            *(uint4*)&A[tid * astr + p] = make_uint4(0, 0, 0, 0);
    }
    __syncthreads();

    const int arow = (w * 16 + l15) * astr;
    f32x4 acc[13];
#pragma unroll
    for (int t = 0; t < 13; ++t) acc[t] = (f32x4){0.f, 0.f, 0.f, 0.f};

    for (int c = 0; c < kch; ++c) {
        bf16x8 a = *(const bf16x8*)&A[arow + c * 32 + lq * 8];
#pragma unroll
        for (int t = 0; t < 13; ++t) {
            bf16x8 b = *(const bf16x8*)&Wt[(size_t)(t * 16 + l15) * kpad + c * 32 + lq * 8];
            acc[t] = __builtin_amdgcn_mfma_f32_16x16x32_bf16(a, b, acc[t], 0, 0, 0);
        }
    }

#pragma unroll
    for (int t = 0; t < 13; ++t) {
        int col = t * 16 + l15;
        if (col >= 200) continue;
        float bs = bias[col];
#pragma unroll
        for (int i = 0; i < 4; ++i) {
            int grow = bm + w * 16 + lq * 4 + i;
            if (grow >= M) continue;
            float v = acc[t][i] + bs;
            OUT[(size_t)grow * 200 + col] = leaky ? leakyf(v) : v;
        }
    }
}

// ---------------- hd[n] = hv[n,:] . e2W[0:200] ----------------
__global__ __launch_bounds__(256) void hd_k(
    const float* __restrict__ hv, const float* __restrict__ e2W,
    float* __restrict__ hd, int Nn)
{
    int wid = blockIdx.x * 4 + (threadIdx.x >> 6);
    int lane = threadIdx.x & 63;
    if (wid >= Nn) return;
    float s = 0.f;
    for (int j = lane; j < G; j += 64) s += hv[(size_t)wid * G + j] * e2W[j];
    for (int off = 32; off; off >>= 1) s += __shfl_down(s, off);
    if (lane == 0) hd[wid] = s;
}

// ============ fused edge kernel (MFMA bf16) ============
__global__ __launch_bounds__(256) void edgefuse_k(
    const float* __restrict__ node, const float* __restrict__ edgef,
    const int* __restrict__ src, const int* __restrict__ dst,
    const unsigned short* __restrict__ W1t, const float* __restrict__ b1,
    const unsigned short* __restrict__ etWt, const float* __restrict__ etb,
    const float* __restrict__ e2W, const float* __restrict__ e2b,
    const float* __restrict__ hd,
    float* __restrict__ sden, float* __restrict__ cacc, int E)
{
    __shared__ __align__(16) unsigned short U[64 * 232];
    __shared__ __align__(16) unsigned short Wt[208 * 40];
    __shared__ float rowlg[64];
    __shared__ float pexp_s[64];
    __shared__ int   dst_s[64];

    const int tid  = threadIdx.x;
    const int w    = tid >> 6;
    const int lane = tid & 63;
    const int l15  = lane & 15;
    const int lq   = lane >> 4;
    const int eb   = blockIdx.x * 64;

    {
        const int r4 = tid >> 2, q = tid & 3;
        const int e  = eb + r4;
        if (e < E) {
            const int se = src[e];
            const float4* np = (const float4*)(node + (size_t)se * NF);
            const float4* ep = (const float4*)(edgef + (size_t)e * EF);
            uint4* rowp = (uint4*)(U + r4 * 200);
#pragma unroll
            for (int i = 0; i < 4; ++i) {
                float4 a = np[q * 8 + 2 * i];
                float4 b = np[q * 8 + 2 * i + 1];
                uint4 u; u.x = pk2(a.x, a.y); u.y = pk2(a.z, a.w);
                u.z = pk2(b.x, b.y); u.w = pk2(b.z, b.w);
                rowp[q * 4 + i] = u;
            }
            uint4* edp = (uint4*)(U + r4 * 200 + 128);
#pragma unroll
            for (int i = 0; i < 2; ++i) {
                float4 a = ep[q * 4 + 2 * i];
                float4 b = ep[q * 4 + 2 * i + 1];
                uint4 u; u.x = pk2(a.x, a.y); u.y = pk2(a.z, a.w);
                u.z = pk2(b.x, b.y); u.w = pk2(b.z, b.w);
                edp[q * 2 + i] = u;
            }
        } else {
            uint4 z = make_uint4(0, 0, 0, 0);
            uint4* rowp = (uint4*)(U + r4 * 200);
#pragma unroll
            for (int i = 0; i < 4; ++i) rowp[q * 4 + i] = z;
            uint4* edp = (uint4*)(U + r4 * 200 + 128);
            edp[q * 2] = z; edp[q * 2 + 1] = z;
        }
        if (tid < 64) dst_s[tid] = (eb + tid < E) ? dst[eb + tid] : 0;
    }
    __syncthreads();

    f32x4 acc[13];
#pragma unroll
    for (int t = 0; t < 13; ++t) acc[t] = (f32x4){0.f, 0.f, 0.f, 0.f};

    for (int c = 0; c < 6; ++c) {
        for (int q = tid; q < 832; q += 256) {
            int n = q >> 2, s = q & 3;
            *(uint4*)(Wt + n * 40 + s * 8) =
                *(const uint4*)(W1t + (size_t)n * 192 + c * 32 + s * 8);
        }
        __syncthreads();
        bf16x8 a = *(const bf16x8*)(U + (w * 16 + l15) * 200 + c * 32 + lq * 8);
#pragma unroll
        for (int t = 0; t < 13; ++t) {
            bf16x8 b = *(const bf16x8*)(Wt + (t * 16 + l15) * 40 + lq * 8);
            acc[t] = __builtin_amdgcn_mfma_f32_16x16x32_bf16(a, b, acc[t], 0, 0, 0);
        }
        __syncthreads();
    }

    float p[4] = {0.f, 0.f, 0.f, 0.f};
#pragma unroll
    for (int t = 0; t < 13; ++t) {
        const int col = t * 16 + l15;
#pragma unroll
        for (int r = 0; r < 4; ++r) {
            const int row = w * 16 + lq * 4 + r;
            float v = 0.f;
            if (col < 200) {
                v = leakyf(acc[t][r] + b1[col]);
                p[r] = fmaf(v, e2W[200 + col], p[r]);
            }
            U[row * 232 + col] = f2bf(v);
        }
    }
    if (tid < 128)
        *(uint4*)(U + (tid >> 1) * 232 + 208 + (tid & 1) * 8) = make_uint4(0, 0, 0, 0);

#pragma unroll
    for (int r = 0; r < 4; ++r) {
        p[r] += __shfl_xor(p[r], 1);
        p[r] += __shfl_xor(p[r], 2);
        p[r] += __shfl_xor(p[r], 4);
        p[r] += __shfl_xor(p[r], 8);
    }
    if (l15 == 0) {
#pragma unroll
        for (int r = 0; r < 4; ++r) rowlg[w * 16 + lq * 4 + r] = p[r];
    }
    __syncthreads();

    if (tid < 64) {
        const int e = eb + tid;
        float pe = 0.f;
        if (e < E) {
            float l = leakyf(rowlg[tid] + hd[dst_s[tid]] + e2b[0]);
            pe = expf(l);
            atomicAdd(&sden[dst_s[tid]], pe);
        }
        pexp_s[tid] = pe;
    }
    __syncthreads();

    f32x4 acc2[13];
#pragma unroll
    for (int t = 0; t < 13; ++t) acc2[t] = (f32x4){0.f, 0.f, 0.f, 0.f};

    for (int c = 0; c < 7; ++c) {
        for (int q = tid; q < 832; q += 256) {
            int n = q >> 2, s = q & 3;
            *(uint4*)(Wt + n * 40 + s * 8) =
                *(const uint4*)(etWt + (size_t)n * 224 + c * 32 + s * 8);
        }
        __syncthreads();
        bf16x8 a = *(const bf16x8*)(U + (w * 16 + l15) * 232 + c * 32 + lq * 8);
#pragma unroll
        for (int t = 0; t < 13; ++t) {
            bf16x8 b = *(const bf16x8*)(Wt + (t * 16 + l15) * 40 + lq * 8);
            acc2[t] = __builtin_amdgcn_mfma_f32_16x16x32_bf16(a, b, acc2[t], 0, 0, 0);
        }
        __syncthreads();
    }

#pragma unroll
    for (int r = 0; r < 4; ++r) {
        const int row = w * 16 + lq * 4 + r;
        const float pe = pexp_s[row];
        if (pe != 0.f) {
            float* base = cacc + (size_t)dst_s[row] * G;
#pragma unroll
            for (int t = 0; t < 13; ++t) {
                const int col = t * 16 + l15;
                if (col < 200)
                    atomicAdd(base + col, pe * (acc2[t][r] + etb[col]));
            }
        }
    }
}

// ============ MFMA GRU: OUT = relu(GRU(elu(X/xdiv), H)) ============
// A(LDS) = [elu(x) pad208 | h pad224] bf16, stride 440.
// Phase 1: r,z = sigm([x|h] @ Wrzt^T + b)   (combined K=416, 26 tiles)
// Phase 2: t = r * (h @ Whnt^T + bh_n)      (K=224, in-register elementwise)
// Phase 3: n = tanh(x @ Wxnt^T + bx_n + t); out = relu((1-z)n + z h)
__global__ __launch_bounds__(256) void grumfma_k(
    const float* __restrict__ X, const float* __restrict__ H,
    const float* __restrict__ xdiv,
    const unsigned short* __restrict__ Wrzt,
    const unsigned short* __restrict__ Wxnt,
    const unsigned short* __restrict__ Whnt,
    const float* __restrict__ bx, const float* __restrict__ bh,
    float* __restrict__ OUT, int M)
{
    __shared__ __align__(16) unsigned short A[64 * 440];
    const int tid = threadIdx.x;
    const int w = tid >> 6, lane = tid & 63, l15 = lane & 15, lq = lane >> 4;
    const int bm = blockIdx.x * 64;

    // ---- stage A ----
    for (int i = tid; i < 64 * 25; i += 256) {
        int r = i / 25, ch = i % 25;
        int grow = bm + r;
        uint4 ux = make_uint4(0, 0, 0, 0), uh = ux;
        if (grow < M) {
            const float4* xp = (const float4*)(X + (size_t)grow * 200 + ch * 8);
            const float4* hp = (const float4*)(H + (size_t)grow * 200 + ch * 8);
            float inv = 1.f;
            if (xdiv) { float dv = xdiv[grow]; inv = (dv > 0.f) ? 1.f / dv : 0.f; }
            float4 a = xp[0], b = xp[1];
            ux.x = pk2(eluf(a.x * inv), eluf(a.y * inv));
            ux.y = pk2(eluf(a.z * inv), eluf(a.w * inv));
            ux.z = pk2(eluf(b.x * inv), eluf(b.y * inv));
            ux.w = pk2(eluf(b.z * inv), eluf(b.w * inv));
            float4 c = hp[0], d = hp[1];
            uh.x = pk2(c.x, c.y); uh.y = pk2(c.z, c.w);
            uh.z = pk2(d.x, d.y); uh.w = pk2(d.z, d.w);
        }
        *(uint4*)&A[r * 440 + ch * 8] = ux;
        *(uint4*)&A[r * 440 + 208 + ch * 8] = uh;
    }
    if (tid < 64) {
        uint4 z = make_uint4(0, 0, 0, 0);
        *(uint4*)&A[tid * 440 + 200] = z;
        *(uint4*)&A[tid * 440 + 408] = z;
        *(uint4*)&A[tid * 440 + 416] = z;
        *(uint4*)&A[tid * 440 + 424] = z;
        *(uint4*)&A[tid * 440 + 432] = z;
    }
    __syncthreads();

    const int arow = (w * 16 + l15) * 440;

    // ---- phase 1: rz (K=416) ----
    f32x4 acc[26];
#pragma unroll
    for (int t = 0; t < 26; ++t) acc[t] = (f32x4){0.f, 0.f, 0.f, 0.f};
    for (int c = 0; c < 13; ++c) {
        bf16x8 a = *(const bf16x8*)&A[arow + c * 32 + lq * 8];
#pragma unroll
        for (int t = 0; t < 26; ++t) {
            bf16x8 b = *(const bf16x8*)&Wrzt[(size_t)(t * 16 + l15) * 416 + c * 32 + lq * 8];
            acc[t] = __builtin_amdgcn_mfma_f32_16x16x32_bf16(a, b, acc[t], 0, 0, 0);
        }
    }
#pragma unroll
    for (int t = 0; t < 13; ++t) {
        int col = t * 16 + l15;
        float br = 0.f, bz = 0.f;
        if (col < 200) {
            br = bx[col] + bh[col];
            bz = bx[200 + col] + bh[200 + col];
        }
#pragma unroll
        for (int i = 0; i < 4; ++i) {
            acc[t][i]      = sigm(acc[t][i] + br);       // r
            acc[13 + t][i] = sigm(acc[13 + t][i] + bz);  // z
        }
    }

    // ---- phase 2: gh_n (K=224), t := r * (gh_n + bh_n) ----
    f32x4 g[13];
#pragma unroll
    for (int t = 0; t < 13; ++t) g[t] = (f32x4){0.f, 0.f, 0.f, 0.f};
    for (int c = 0; c < 7; ++c) {
        bf16x8 a = *(const bf16x8*)&A[arow + 208 + c * 32 + lq * 8];
#pragma unroll
        for (int t = 0; t < 13; ++t) {
            bf16x8 b = *(const bf16x8*)&Whnt[(size_t)(t * 16 + l15) * 224 + c * 32 + lq * 8];
            g[t] = __builtin_amdgcn_mfma_f32_16x16x32_bf16(a, b, g[t], 0, 0, 0);
        }
    }
#pragma unroll
    for (int t = 0; t < 13; ++t) {
        int col = t * 16 + l15;
        float bn = (col < 200) ? bh[400 + col] : 0.f;
#pragma unroll
        for (int i = 0; i < 4; ++i)
            acc[t][i] = acc[t][i] * (g[t][i] + bn);      // r*(ghn+bhn)
    }

    // ---- phase 3: gx_n (K=224; cols 208..223 hit h-data but Wxnt=0 there) ----
#pragma unroll
    for (int t = 0; t < 13; ++t) g[t] = (f32x4){0.f, 0.f, 0.f, 0.f};
    for (int c = 0; c < 7; ++c) {
        bf16x8 a = *(const bf16x8*)&A[arow + c * 32 + lq * 8];
#pragma unroll
        for (int t = 0; t < 13; ++t) {
            bf16x8 b = *(const bf16x8*)&Wxnt[(size_t)(t * 16 + l15) * 224 + c * 32 + lq * 8];
            g[t] = __builtin_amdgcn_mfma_f32_16x16x32_bf16(a, b, g[t], 0, 0, 0);
        }
    }

#pragma unroll
    for (int t = 0; t < 13; ++t) {
        int col = t * 16 + l15;
        if (col >= 200) continue;
        float bn = bx[400 + col];
#pragma unroll
        for (int i = 0; i < 4; ++i) {
            int row = w * 16 + lq * 4 + i;
            int grow = bm + row;
            if (grow >= M) continue;
            float nn = tanhf(g[t][i] + bn + acc[t][i]);
            float zz = acc[13 + t][i];
            float h  = bf2f(A[row * 440 + 208 + col]);
            float o  = (1.f - zz) * nn + zz * h;
            OUT[(size_t)grow * 200 + col] = fmaxf(o, 0.f);
        }
    }
}

// ------------- layer-2 logits -------------
__global__ __launch_bounds__(256) void logits2_k(
    const float* __restrict__ h0,
    const float* __restrict__ W, const float* __restrict__ b,
    const int* __restrict__ src, const int* __restrict__ dst,
    float* __restrict__ lg, float* __restrict__ sden, int E)
{
    int wid = blockIdx.x * 4 + (threadIdx.x >> 6);
    int lane = threadIdx.x & 63;
    if (wid >= E) return;
    int d = dst[wid], s_ = src[wid];
    float sum = 0.f;
    for (int j = lane; j < G; j += 64)
        sum += h0[(size_t)d * G + j] * W[j] + h0[(size_t)s_ * G + j] * W[G + j];
    for (int off = 32; off; off >>= 1) sum += __shfl_down(sum, off);
    if (lane == 0) {
        float l = leakyf(sum + b[0]);
        lg[wid] = l;
        atomicAdd(&sden[d], expf(l));
    }
}

// ------------- c2[dst] += hvp[src] * (exp(lg)/sden[dst] + 1) -------------
__global__ __launch_bounds__(256) void c2_k(
    const float* __restrict__ hvp,
    const float* __restrict__ lg, const float* __restrict__ sden,
    const int* __restrict__ src, const int* __restrict__ dst,
    float* __restrict__ cacc, int E)
{
    int wid = blockIdx.x * 4 + (threadIdx.x >> 6);
    int lane = threadIdx.x & 63;
    if (wid >= E) return;
    int d = dst[wid], s_ = src[wid];
    float a2 = expf(lg[wid]) / sden[d] + 1.0f;
    for (int j = lane; j < G; j += 64)
        atomicAdd(&cacc[(size_t)d * G + j], hvp[(size_t)s_ * G + j] * a2);
}

// ------------- batchnorm stats -------------
__global__ __launch_bounds__(256) void bnstat_k(
    const float* __restrict__ h1, float* __restrict__ stats, long total)
{
    __shared__ float ls[2 * G];
    for (int t = threadIdx.x; t < 2 * G; t += 256) ls[t] = 0.f;
    __syncthreads();
    for (long idx = (long)blockIdx.x * 256 + threadIdx.x; idx < total;
         idx += (long)gridDim.x * 256) {
        float v = h1[idx];
        int c = (int)(idx % G);
        atomicAdd(&ls[c], v);
        atomicAdd(&ls[G + c], v * v);
    }
    __syncthreads();
    for (int t = threadIdx.x; t < 2 * G; t += 256) atomicAdd(&stats[t], ls[t]);
}

// ------------- out = h0(=in d_out) + bn(h1), in place -------------
__global__ __launch_bounds__(256) void final_k(
    float* __restrict__ out, const float* __restrict__ h1,
    const float* __restrict__ stats,
    const float* __restrict__ g, const float* __restrict__ bb, int Nn)
{
    long total = (long)Nn * G;
    for (long idx = (long)blockIdx.x * 256 + threadIdx.x; idx < total;
         idx += (long)gridDim.x * 256) {
        int c = (int)(idx % G);
        float mu  = stats[c] / Nn;
        float var = stats[G + c] / Nn - mu * mu;
        float xh  = (h1[idx] - mu) * rsqrtf(var + 1e-5f);
        out[idx] = out[idx] + g[c] * xh + bb[c];
    }
}

extern "C" void kernel_launch(void* const* d_in, const int* in_sizes, int n_in,
                              void* d_out, int out_size, void* d_ws, size_t ws_size,
                              hipStream_t stream)
{
    const float* node_feats = (const float*)d_in[0];
    const float* edge_feats = (const float*)d_in[1];
    const float* gc_node_W  = (const float*)d_in[2];
    const float* gc_node_b  = (const float*)d_in[3];
    const float* gc_e1_W    = (const float*)d_in[4];
    const float* gc_e1_b    = (const float*)d_in[5];
    const float* gc_e2_W    = (const float*)d_in[6];
    const float* gc_e2_b    = (const float*)d_in[7];
    const float* gc_et_W    = (const float*)d_in[8];
    const float* gc_et_b    = (const float*)d_in[9];
    const float* gc_gru_Wx  = (const float*)d_in[10];
    const float* gc_gru_Wh  = (const float*)d_in[11];
    const float* gc_gru_bx  = (const float*)d_in[12];
    const float* gc_gru_bh  = (const float*)d_in[13];
    const float* l1_e_W     = (const float*)d_in[14];
    const float* l1_e_b     = (const float*)d_in[15];
    const float* l1_pn_W    = (const float*)d_in[16];
    const float* l1_pn_b    = (const float*)d_in[17];
    const float* l1_gru_Wx  = (const float*)d_in[18];
    const float* l1_gru_Wh  = (const float*)d_in[19];
    const float* l1_gru_bx  = (const float*)d_in[20];
    const float* l1_gru_bh  = (const float*)d_in[21];
    const float* l1_bn_g    = (const float*)d_in[22];
    const float* l1_bn_b    = (const float*)d_in[23];
    const int*   src        = (const int*)d_in[24];
    const int*   dst        = (const int*)d_in[25];

    const int Nn = in_sizes[0] / NF;
    const int E  = in_sizes[24];

    float* ws = (float*)d_ws;
    size_t o = 0;
    float* hv    = ws + o; o += (size_t)Nn * G;   // hv_new -> hvp -> h1
    float* cbuf  = ws + o; o += (size_t)Nn * G;   // cacc(layer1) -> c2
    float* lg    = ws + o; o += (size_t)E;
    float* sden  = ws + o; o += (size_t)Nn;
    float* hd    = ws + o; o += (size_t)Nn;
    float* stats = ws + o; o += 512;
    unsigned short* W1t_g   = (unsigned short*)(ws + o); o += (208 * 192) / 2;
    unsigned short* etWt_g  = (unsigned short*)(ws + o); o += (208 * 224) / 2;
    unsigned short* ncWt_g  = (unsigned short*)(ws + o); o += (208 * 128) / 2;
    unsigned short* pnWt_g  = (unsigned short*)(ws + o); o += (208 * 224) / 2;
    unsigned short* Wrzt1_g = (unsigned short*)(ws + o); o += (416 * 416) / 2;
    unsigned short* Wxnt1_g = (unsigned short*)(ws + o); o += (208 * 224) / 2;
    unsigned short* Whnt1_g = (unsigned short*)(ws + o); o += (208 * 224) / 2;
    unsigned short* Wrzt2_g = (unsigned short*)(ws + o); o += (416 * 416) / 2;
    unsigned short* Wxnt2_g = (unsigned short*)(ws + o); o += (208 * 224) / 2;
    unsigned short* Whnt2_g = (unsigned short*)(ws + o); o += (208 * 224) / 2;
    // total ~21.7M floats ~= 87 MB

    float* h0  = (float*)d_out;
    float* hvp = hv;
    float* h1  = hv;

    const int gN64 = (Nn + 63) / 64;
    const int gE64 = (E + 63) / 64;
    const int eWaves = (E + 3) / 4;
    const int nWaves = (Nn + 3) / 4;
    const long totNG = (long)Nn * G;

    // ---------- weight prep ----------
    tprep_k<<<128, 256, 0, stream>>>(gc_e1_W,   W1t_g,  192, 192, 200, 200);
    tprep_k<<<128, 256, 0, stream>>>(gc_et_W,   etWt_g, 200, 224, 200, 200);
    tprep_k<<<128, 256, 0, stream>>>(gc_node_W, ncWt_g, 128, 128, 200, 200);
    tprep_k<<<128, 256, 0, stream>>>(l1_pn_W,   pnWt_g, 200, 224, 200, 200);
    wprep2_k<<<256, 256, 0, stream>>>(gc_gru_Wx, gc_gru_Wh, Wrzt1_g, Wxnt1_g, Whnt1_g);
    wprep2_k<<<256, 256, 0, stream>>>(l1_gru_Wx, l1_gru_Wh, Wrzt2_g, Wxnt2_g, Whnt2_g);

    // ---------- GetContext ----------
    hipMemsetAsync(sden, 0, (size_t)Nn * sizeof(float), stream);
    hipMemsetAsync(cbuf, 0, (size_t)Nn * G * sizeof(float), stream);
    hipMemsetAsync(stats, 0, 512 * sizeof(float), stream);

    // hv = leaky(node @ ncW + b)
    mgemm_k<<<gN64, 256, 0, stream>>>(node_feats, ncWt_g, gc_node_b, hv,
                                      Nn, 128, 4, 136, 1);

    hd_k<<<nWaves, 256, 0, stream>>>(hv, gc_e2_W, hd, Nn);

    edgefuse_k<<<gE64, 256, 0, stream>>>(
        node_feats, edge_feats, src, dst,
        W1t_g, gc_e1_b, etWt_g, gc_et_b,
        gc_e2_W, gc_e2_b, hd, sden, cbuf, E);

    // h0 = relu(GRU(elu(cbuf / sden), hv))
    grumfma_k<<<gN64, 256, 0, stream>>>(
        cbuf, hv, sden, Wrzt1_g, Wxnt1_g, Whnt1_g,
        gc_gru_bx, gc_gru_bh, h0, Nn);

    // ---------- GNNLayer ----------
    hipMemsetAsync(sden, 0, (size_t)Nn * sizeof(float), stream);

    logits2_k<<<eWaves, 256, 0, stream>>>(h0, l1_e_W, l1_e_b, src, dst, lg, sden, E);

    // hvp = h0 @ pnW + b
    mgemm_k<<<gN64, 256, 0, stream>>>(h0, pnWt_g, l1_pn_b, hvp,
                                      Nn, 200, 7, 232, 0);

    hipMemsetAsync(cbuf, 0, (size_t)Nn * G * sizeof(float), stream);

    c2_k<<<eWaves, 256, 0, stream>>>(hvp, lg, sden, src, dst, cbuf, E);

    // h1 = relu(GRU(elu(c2), h0))
    grumfma_k<<<gN64, 256, 0, stream>>>(
        cbuf, h0, nullptr, Wrzt2_g, Wxnt2_g, Whnt2_g,
        l1_gru_bx, l1_gru_bh, h1, Nn);

    bnstat_k<<<2048, 256, 0, stream>>>(h1, stats, totNG);
    final_k<<<2048, 256, 0, stream>>>((float*)d_out, h1, stats,
                                      l1_bn_g, l1_bn_b, Nn);
}

// Round 6
// 1465.820 us; speedup vs baseline: 3.0727x; 1.3200x over previous
//
#include <hip/hip_runtime.h>
#include <math.h>

#define G 200
#define NF 128
#define EF 64

typedef __attribute__((ext_vector_type(8))) short bf16x8;
typedef __attribute__((ext_vector_type(4))) float f32x4;

__device__ __forceinline__ float leakyf(float x) { return x > 0.f ? x : 0.01f * x; }
__device__ __forceinline__ float eluf(float x)   { return x > 0.f ? x : (expf(x) - 1.f); }
__device__ __forceinline__ float sigm(float x)   { return 1.f / (1.f + expf(-x)); }

__device__ __forceinline__ unsigned short f2bf(float x) {
    union { float f; unsigned int u; } v; v.f = x;
    unsigned int r = v.u + 0x7FFF + ((v.u >> 16) & 1);   // RNE
    return (unsigned short)(r >> 16);
}
__device__ __forceinline__ float bf2f(unsigned short u) {
    union { unsigned int i; float f; } v; v.i = ((unsigned int)u) << 16;
    return v.f;
}
__device__ __forceinline__ unsigned int pk2(float a, float b) {
    return (unsigned int)f2bf(a) | ((unsigned int)f2bf(b) << 16);
}

// ---------- generic weight transpose+bf16 prep: Wt[208][kpad] = W[k][n] ----------
__global__ __launch_bounds__(256) void tprep_k(
    const float* __restrict__ W, unsigned short* __restrict__ Wt,
    int Kreal, int kpad, int Nstride, int Nreal)
{
    int total = 208 * kpad;
    for (int i = blockIdx.x * 256 + threadIdx.x; i < total; i += gridDim.x * 256) {
        int n = i / kpad, k = i % kpad;
        Wt[i] = (n < Nreal && k < Kreal) ? f2bf(W[(size_t)k * Nstride + n]) : 0;
    }
}

// ---------- GRU weight prep ----------
__global__ __launch_bounds__(256) void wprep2_k(
    const float* __restrict__ Wx, const float* __restrict__ Wh,
    unsigned short* __restrict__ Wrzt,
    unsigned short* __restrict__ Wxnt, unsigned short* __restrict__ Whnt)
{
    const int t1 = 416 * 416;
    for (int i = blockIdx.x * 256 + threadIdx.x; i < t1; i += gridDim.x * 256) {
        int n = i / 416, k = i % 416;
        int gg = (n >= 208) ? 1 : 0;
        int cc = n - gg * 208;
        float v = 0.f;
        if (cc < 200) {
            if (k < 200)                  v = Wx[(size_t)k * 600 + gg * 200 + cc];
            else if (k >= 208 && k < 408) v = Wh[(size_t)(k - 208) * 600 + gg * 200 + cc];
        }
        Wrzt[i] = f2bf(v);
    }
    const int t2 = 208 * 224;
    for (int i = blockIdx.x * 256 + threadIdx.x; i < t2; i += gridDim.x * 256) {
        int n = i / 224, k = i % 224;
        bool ok = (n < 200 && k < 200);
        Wxnt[i] = ok ? f2bf(Wx[(size_t)k * 600 + 400 + n]) : 0;
        Whnt[i] = ok ? f2bf(Wh[(size_t)k * 600 + 400 + n]) : 0;
    }
}

// ---------- CSR build ----------
__global__ __launch_bounds__(256) void hist_k(
    const int* __restrict__ dst, int* __restrict__ cnt, int E)
{
    int i = blockIdx.x * 256 + threadIdx.x;
    if (i < E) atomicAdd(&cnt[dst[i]], 1);
}

__global__ __launch_bounds__(256) void scan_k(
    const int* __restrict__ cnt, int* __restrict__ offs,
    int* __restrict__ cursor, int Nn)
{
    __shared__ int wsum[4];
    const int tid = threadIdx.x;
    const int lane = tid & 63, wv = tid >> 6;
    int carry = 0;
    const int CH = 8;
    for (int base = 0; base < Nn; base += 256 * CH) {
        int v[CH]; int tsum = 0;
        int i0 = base + tid * CH;
#pragma unroll
        for (int j = 0; j < CH; ++j) {
            v[j] = (i0 + j < Nn) ? cnt[i0 + j] : 0;
            tsum += v[j];
        }
        int x = tsum;                       // inclusive scan across the wave
        for (int off = 1; off < 64; off <<= 1) {
            int t = __shfl_up(x, off);
            if (lane >= off) x += t;
        }
        if (lane == 63) wsum[wv] = x;
        __syncthreads();
        int wbase = 0;
#pragma unroll
        for (int wq = 0; wq < 4; ++wq) wbase += (wq < wv) ? wsum[wq] : 0;
        int gtot = wsum[0] + wsum[1] + wsum[2] + wsum[3];
        int run = carry + wbase + (x - tsum);
#pragma unroll
        for (int j = 0; j < CH; ++j) {
            int idx = i0 + j;
            if (idx < Nn) { offs[idx] = run; cursor[idx] = run; }
            run += v[j];
        }
        carry += gtot;
        __syncthreads();
    }
    if (tid == 0) offs[Nn] = carry;
}

__global__ __launch_bounds__(256) void scatter_k(
    const int* __restrict__ src, const int* __restrict__ dst,
    int* __restrict__ cursor, int* __restrict__ eidC,
    int* __restrict__ srcC, int* __restrict__ dstC, int E)
{
    int i = blockIdx.x * 256 + threadIdx.x;
    if (i < E) {
        int d = dst[i];
        int pos = atomicAdd(&cursor[d], 1);
        eidC[pos] = i; srcC[pos] = src[i]; dstC[pos] = d;
    }
}

// ---------- dense MFMA GEMM: OUT[M,200] = epi((X/xdiv)[M,Kreal] @ W + bias*gate) ----------
__global__ __launch_bounds__(256) void mgemm_k(
    const float* __restrict__ X, const unsigned short* __restrict__ Wt,
    const float* __restrict__ bias, float* __restrict__ OUT,
    int M, int Kreal, int kch, int astr, int leaky,
    const float* __restrict__ xdiv)
{
    __shared__ __align__(16) unsigned short A[64 * 232];
    const int tid = threadIdx.x;
    const int w = tid >> 6, lane = tid & 63, l15 = lane & 15, lq = lane >> 4;
    const int bm = blockIdx.x * 64;
    const int kpad = kch * 32;
    const int nch8 = Kreal >> 3;

    for (int i = tid; i < 64 * nch8; i += 256) {
        int r = i / nch8, ch = i % nch8;
        int grow = bm + r;
        uint4 u = make_uint4(0, 0, 0, 0);
        if (grow < M) {
            const float4* xp = (const float4*)(X + (size_t)grow * Kreal + ch * 8);
            float inv = 1.f;
            if (xdiv) { float dv = xdiv[grow]; inv = (dv > 0.f) ? 1.f / dv : 0.f; }
            float4 a = xp[0], b = xp[1];
            u.x = pk2(a.x * inv, a.y * inv); u.y = pk2(a.z * inv, a.w * inv);
            u.z = pk2(b.x * inv, b.y * inv); u.w = pk2(b.z * inv, b.w * inv);
        }
        *(uint4*)&A[r * astr + ch * 8] = u;
    }
    if (tid < 64) {
        for (int p = Kreal; p < kpad; p += 8)
            *(uint4*)&A[tid * astr + p] = make_uint4(0, 0, 0, 0);
    }
    __syncthreads();

    const int arow = (w * 16 + l15) * astr;
    f32x4 acc[13];
#pragma unroll
    for (int t = 0; t < 13; ++t) acc[t] = (f32x4){0.f, 0.f, 0.f, 0.f};

    for (int c = 0; c < kch; ++c) {
        bf16x8 a = *(const bf16x8*)&A[arow + c * 32 + lq * 8];
#pragma unroll
        for (int t = 0; t < 13; ++t) {
            bf16x8 b = *(const bf16x8*)&Wt[(size_t)(t * 16 + l15) * kpad + c * 32 + lq * 8];
            acc[t] = __builtin_amdgcn_mfma_f32_16x16x32_bf16(a, b, acc[t], 0, 0, 0);
        }
    }

    float rg[4];
#pragma unroll
    for (int i = 0; i < 4; ++i) {
        int grow = bm + w * 16 + lq * 4 + i;
        rg[i] = 1.f;
        if (xdiv && grow < M) rg[i] = (xdiv[grow] > 0.f) ? 1.f : 0.f;
    }

#pragma unroll
    for (int t = 0; t < 13; ++t) {
        int col = t * 16 + l15;
        if (col >= 200) continue;
        float bs = bias[col];
#pragma unroll
        for (int i = 0; i < 4; ++i) {
            int grow = bm + w * 16 + lq * 4 + i;
            if (grow >= M) continue;
            float v = acc[t][i] + bs * rg[i];
            OUT[(size_t)grow * 200 + col] = leaky ? leakyf(v) : v;
        }
    }
}

// ---------------- hd[n] = x[n,:] . W[0:200] ----------------
__global__ __launch_bounds__(256) void hd_k(
    const float* __restrict__ x, const float* __restrict__ W,
    float* __restrict__ hd, int Nn)
{
    int wid = blockIdx.x * 4 + (threadIdx.x >> 6);
    int lane = threadIdx.x & 63;
    if (wid >= Nn) return;
    float s = 0.f;
    for (int j = lane; j < G; j += 64) s += x[(size_t)wid * G + j] * W[j];
    for (int off = 32; off; off >>= 1) s += __shfl_down(s, off);
    if (lane == 0) hd[wid] = s;
}

// ============ fused edge kernel (CSR order, MFMA bf16) ============
// he1 = leaky(concat(node[srcC],edge[eidC]) @ W1 + b1); pexp = exp(leaky(he1.w2+hd[dst]+b2))
// sden[dst] += pexp;  hacc[dst] += pexp*he1  (segmented: CSR-sorted dst)
__global__ __launch_bounds__(256) void edgefuse2_k(
    const float* __restrict__ node, const float* __restrict__ edgef,
    const int* __restrict__ srcC, const int* __restrict__ dstC,
    const int* __restrict__ eidC,
    const unsigned short* __restrict__ W1t, const float* __restrict__ b1,
    const float* __restrict__ e2W, const float* __restrict__ e2b,
    const float* __restrict__ hd,
    float* __restrict__ sden, float* __restrict__ hacc, int E)
{
    __shared__ __align__(16) unsigned short U[64 * 216];   // A (K=192) then he1 bf16
    __shared__ __align__(16) unsigned short Wt[208 * 40];
    __shared__ float rowlg[64];
    __shared__ float pexp_s[64];
    __shared__ int   dst_s[64];

    const int tid  = threadIdx.x;
    const int w    = tid >> 6;
    const int lane = tid & 63;
    const int l15  = lane & 15;
    const int lq   = lane >> 4;
    const int eb   = blockIdx.x * 64;

    // ---- stage A = concat(node[srcC], edge[eidC]) bf16, stride 216 ----
    {
        const int r4 = tid >> 2, q = tid & 3;
        const int pos = eb + r4;
        if (pos < E) {
            const int se = srcC[pos];
            const int ei = eidC[pos];
            const float4* np = (const float4*)(node + (size_t)se * NF);
            const float4* ep = (const float4*)(edgef + (size_t)ei * EF);
            uint4* rowp = (uint4*)(U + r4 * 216);
#pragma unroll
            for (int i = 0; i < 4; ++i) {
                float4 a = np[q * 8 + 2 * i];
                float4 b = np[q * 8 + 2 * i + 1];
                uint4 u; u.x = pk2(a.x, a.y); u.y = pk2(a.z, a.w);
                u.z = pk2(b.x, b.y); u.w = pk2(b.z, b.w);
                rowp[q * 4 + i] = u;
            }
            uint4* edp = (uint4*)(U + r4 * 216 + 128);
#pragma unroll
            for (int i = 0; i < 2; ++i) {
                float4 a = ep[q * 4 + 2 * i];
                float4 b = ep[q * 4 + 2 * i + 1];
                uint4 u; u.x = pk2(a.x, a.y); u.y = pk2(a.z, a.w);
                u.z = pk2(b.x, b.y); u.w = pk2(b.z, b.w);
                edp[q * 2 + i] = u;
            }
        } else {
            uint4 z = make_uint4(0, 0, 0, 0);
            uint4* rowp = (uint4*)(U + r4 * 216);
#pragma unroll
            for (int i = 0; i < 4; ++i) rowp[q * 4 + i] = z;
            uint4* edp = (uint4*)(U + r4 * 216 + 128);
            edp[q * 2] = z; edp[q * 2 + 1] = z;
        }
        if (tid < 64) dst_s[tid] = (eb + tid < E) ? dstC[eb + tid] : -1;
    }
    __syncthreads();

    // ---- he1: A[64][192] @ W1 -> 64x208 ----
    f32x4 acc[13];
#pragma unroll
    for (int t = 0; t < 13; ++t) acc[t] = (f32x4){0.f, 0.f, 0.f, 0.f};

    for (int c = 0; c < 6; ++c) {
        for (int q = tid; q < 832; q += 256) {
            int n = q >> 2, s = q & 3;
            *(uint4*)(Wt + n * 40 + s * 8) =
                *(const uint4*)(W1t + (size_t)n * 192 + c * 32 + s * 8);
        }
        __syncthreads();
        bf16x8 a = *(const bf16x8*)(U + (w * 16 + l15) * 216 + c * 32 + lq * 8);
#pragma unroll
        for (int t = 0; t < 13; ++t) {
            bf16x8 b = *(const bf16x8*)(Wt + (t * 16 + l15) * 40 + lq * 8);
            acc[t] = __builtin_amdgcn_mfma_f32_16x16x32_bf16(a, b, acc[t], 0, 0, 0);
        }
        __syncthreads();
    }

    // ---- epilogue: leaky+bias -> he1 bf16 (U), logit partials ----
    float p[4] = {0.f, 0.f, 0.f, 0.f};
#pragma unroll
    for (int t = 0; t < 13; ++t) {
        const int col = t * 16 + l15;
#pragma unroll
        for (int r = 0; r < 4; ++r) {
            const int row = w * 16 + lq * 4 + r;
            float v = 0.f;
            if (col < 200) {
                v = leakyf(acc[t][r] + b1[col]);
                p[r] = fmaf(v, e2W[200 + col], p[r]);
            }
            U[row * 216 + col] = f2bf(v);
        }
    }
#pragma unroll
    for (int r = 0; r < 4; ++r) {
        p[r] += __shfl_xor(p[r], 1);
        p[r] += __shfl_xor(p[r], 2);
        p[r] += __shfl_xor(p[r], 4);
        p[r] += __shfl_xor(p[r], 8);
    }
    if (l15 == 0) {
#pragma unroll
        for (int r = 0; r < 4; ++r) rowlg[w * 16 + lq * 4 + r] = p[r];
    }
    __syncthreads();

    if (tid < 64) {
        float pe = 0.f;
        if (eb + tid < E) {
            float l = leakyf(rowlg[tid] + hd[dst_s[tid]] + e2b[0]);
            pe = expf(l);
            atomicAdd(&sden[dst_s[tid]], pe);
        }
        pexp_s[tid] = pe;
    }
    __syncthreads();

    // ---- segmented scatter: hacc[d][c] += sum_{rows with dst==d} pexp*he1 ----
    if (tid < 200) {
        const int c = tid;
        float s = 0.f;
        int cur = dst_s[0];
        for (int r = 0; r < 64; ++r) {
            int d = dst_s[r];
            if (d < 0) break;
            if (d != cur) {
                atomicAdd(&hacc[(size_t)cur * 200 + c], s);
                s = 0.f; cur = d;
            }
            s = fmaf(pexp_s[r], bf2f(U[r * 216 + c]), s);
        }
        atomicAdd(&hacc[(size_t)cur * 200 + c], s);
    }
}

// ============ MFMA GRU: OUT = relu(GRU(elu(X/xdiv), H)) ============
__global__ __launch_bounds__(256) void grumfma_k(
    const float* __restrict__ X, const float* __restrict__ H,
    const float* __restrict__ xdiv,
    const unsigned short* __restrict__ Wrzt,
    const unsigned short* __restrict__ Wxnt,
    const unsigned short* __restrict__ Whnt,
    const float* __restrict__ bx, const float* __restrict__ bh,
    float* __restrict__ OUT, int M)
{
    __shared__ __align__(16) unsigned short A[64 * 440];
    const int tid = threadIdx.x;
    const int w = tid >> 6, lane = tid & 63, l15 = lane & 15, lq = lane >> 4;
    const int bm = blockIdx.x * 64;

    for (int i = tid; i < 64 * 25; i += 256) {
        int r = i / 25, ch = i % 25;
        int grow = bm + r;
        uint4 ux = make_uint4(0, 0, 0, 0), uh = ux;
        if (grow < M) {
            const float4* xp = (const float4*)(X + (size_t)grow * 200 + ch * 8);
            const float4* hp = (const float4*)(H + (size_t)grow * 200 + ch * 8);
            float inv = 1.f;
            if (xdiv) { float dv = xdiv[grow]; inv = (dv > 0.f) ? 1.f / dv : 0.f; }
            float4 a = xp[0], b = xp[1];
            ux.x = pk2(eluf(a.x * inv), eluf(a.y * inv));
            ux.y = pk2(eluf(a.z * inv), eluf(a.w * inv));
            ux.z = pk2(eluf(b.x * inv), eluf(b.y * inv));
            ux.w = pk2(eluf(b.z * inv), eluf(b.w * inv));
            float4 c = hp[0], d = hp[1];
            uh.x = pk2(c.x, c.y); uh.y = pk2(c.z, c.w);
            uh.z = pk2(d.x, d.y); uh.w = pk2(d.z, d.w);
        }
        *(uint4*)&A[r * 440 + ch * 8] = ux;
        *(uint4*)&A[r * 440 + 208 + ch * 8] = uh;
    }
    if (tid < 64) {
        uint4 z = make_uint4(0, 0, 0, 0);
        *(uint4*)&A[tid * 440 + 200] = z;
        *(uint4*)&A[tid * 440 + 408] = z;
        *(uint4*)&A[tid * 440 + 416] = z;
        *(uint4*)&A[tid * 440 + 424] = z;
        *(uint4*)&A[tid * 440 + 432] = z;
    }
    __syncthreads();

    const int arow = (w * 16 + l15) * 440;

    f32x4 acc[26];
#pragma unroll
    for (int t = 0; t < 26; ++t) acc[t] = (f32x4){0.f, 0.f, 0.f, 0.f};
    for (int c = 0; c < 13; ++c) {
        bf16x8 a = *(const bf16x8*)&A[arow + c * 32 + lq * 8];
#pragma unroll
        for (int t = 0; t < 26; ++t) {
            bf16x8 b = *(const bf16x8*)&Wrzt[(size_t)(t * 16 + l15) * 416 + c * 32 + lq * 8];
            acc[t] = __builtin_amdgcn_mfma_f32_16x16x32_bf16(a, b, acc[t], 0, 0, 0);
        }
    }
#pragma unroll
    for (int t = 0; t < 13; ++t) {
        int col = t * 16 + l15;
        float br = 0.f, bz = 0.f;
        if (col < 200) {
            br = bx[col] + bh[col];
            bz = bx[200 + col] + bh[200 + col];
        }
#pragma unroll
        for (int i = 0; i < 4; ++i) {
            acc[t][i]      = sigm(acc[t][i] + br);
            acc[13 + t][i] = sigm(acc[13 + t][i] + bz);
        }
    }

    f32x4 g[13];
#pragma unroll
    for (int t = 0; t < 13; ++t) g[t] = (f32x4){0.f, 0.f, 0.f, 0.f};
    for (int c = 0; c < 7; ++c) {
        bf16x8 a = *(const bf16x8*)&A[arow + 208 + c * 32 + lq * 8];
#pragma unroll
        for (int t = 0; t < 13; ++t) {
            bf16x8 b = *(const bf16x8*)&Whnt[(size_t)(t * 16 + l15) * 224 + c * 32 + lq * 8];
            g[t] = __builtin_amdgcn_mfma_f32_16x16x32_bf16(a, b, g[t], 0, 0, 0);
        }
    }
#pragma unroll
    for (int t = 0; t < 13; ++t) {
        int col = t * 16 + l15;
        float bn = (col < 200) ? bh[400 + col] : 0.f;
#pragma unroll
        for (int i = 0; i < 4; ++i)
            acc[t][i] = acc[t][i] * (g[t][i] + bn);
    }

#pragma unroll
    for (int t = 0; t < 13; ++t) g[t] = (f32x4){0.f, 0.f, 0.f, 0.f};
    for (int c = 0; c < 7; ++c) {
        bf16x8 a = *(const bf16x8*)&A[arow + c * 32 + lq * 8];
#pragma unroll
        for (int t = 0; t < 13; ++t) {
            bf16x8 b = *(const bf16x8*)&Wxnt[(size_t)(t * 16 + l15) * 224 + c * 32 + lq * 8];
            g[t] = __builtin_amdgcn_mfma_f32_16x16x32_bf16(a, b, g[t], 0, 0, 0);
        }
    }

#pragma unroll
    for (int t = 0; t < 13; ++t) {
        int col = t * 16 + l15;
        if (col >= 200) continue;
        float bn = bx[400 + col];
#pragma unroll
        for (int i = 0; i < 4; ++i) {
            int row = w * 16 + lq * 4 + i;
            int grow = bm + row;
            if (grow >= M) continue;
            float nn = tanhf(g[t][i] + bn + acc[t][i]);
            float zz = acc[13 + t][i];
            float h  = bf2f(A[row * 440 + 208 + col]);
            float o  = (1.f - zz) * nn + zz * h;
            OUT[(size_t)grow * 200 + col] = fmaxf(o, 0.f);
        }
    }
}

// ============ layer-2: node-centric logits + softmax + c2 gather (no atomics) ============
__global__ __launch_bounds__(256) void layer2_k(
    const float* __restrict__ h0, const float* __restrict__ hvp,
    const float* __restrict__ hd2,
    const float* __restrict__ W, const float* __restrict__ b,
    const int* __restrict__ offs, const int* __restrict__ srcC,
    float* __restrict__ c2, int Nn)
{
    __shared__ float pes[4][64];
    const int wv = threadIdx.x >> 6;
    const int lane = threadIdx.x & 63;
    const int n = blockIdx.x * 4 + wv;
    if (n >= Nn) return;

    const int base = offs[n], end = offs[n + 1];
    const float hdn = hd2[n] + b[0];

    float ssum = 0.f;
    for (int pos = base; pos < end; ++pos) {
        const float* hr = h0 + (size_t)srcC[pos] * 200;
        float part = hr[lane] * W[200 + lane]
                   + hr[64 + lane] * W[264 + lane]
                   + hr[128 + lane] * W[328 + lane];
        if (lane < 8) part += hr[192 + lane] * W[392 + lane];
        for (int off = 32; off; off >>= 1) part += __shfl_xor(part, off);
        float pe = expf(leakyf(part + hdn));
        ssum += pe;
        int i = pos - base;
        if (i < 64 && lane == 0) pes[wv][i] = pe;
    }
    float inv = (end > base) ? 1.f / ssum : 0.f;

    float a0 = 0.f, a1 = 0.f, a2v = 0.f, a3 = 0.f;
    for (int pos = base; pos < end; ++pos) {
        int i = pos - base;
        float pe;
        if (i < 64) pe = pes[wv][i];
        else {   // vanishingly rare (deg > 64): recompute
            const float* hr = h0 + (size_t)srcC[pos] * 200;
            float part = hr[lane] * W[200 + lane]
                       + hr[64 + lane] * W[264 + lane]
                       + hr[128 + lane] * W[328 + lane];
            if (lane < 8) part += hr[192 + lane] * W[392 + lane];
            for (int off = 32; off; off >>= 1) part += __shfl_xor(part, off);
            pe = expf(leakyf(part + hdn));
        }
        float aw = pe * inv + 1.f;
        const float* vr = hvp + (size_t)srcC[pos] * 200;
        a0  += aw * vr[lane];
        a1  += aw * vr[64 + lane];
        a2v += aw * vr[128 + lane];
        if (lane < 8) a3 += aw * vr[192 + lane];
    }
    float* out = c2 + (size_t)n * 200;
    out[lane] = a0; out[64 + lane] = a1; out[128 + lane] = a2v;
    if (lane < 8) out[192 + lane] = a3;
}

// ------------- batchnorm stats -------------
__global__ __launch_bounds__(256) void bnstat_k(
    const float* __restrict__ h1, float* __restrict__ stats, long total)
{
    __shared__ float ls[2 * G];
    for (int t = threadIdx.x; t < 2 * G; t += 256) ls[t] = 0.f;
    __syncthreads();
    for (long idx = (long)blockIdx.x * 256 + threadIdx.x; idx < total;
         idx += (long)gridDim.x * 256) {
        float v = h1[idx];
        int c = (int)(idx % G);
        atomicAdd(&ls[c], v);
        atomicAdd(&ls[G + c], v * v);
    }
    __syncthreads();
    for (int t = threadIdx.x; t < 2 * G; t += 256) atomicAdd(&stats[t], ls[t]);
}

// ------------- out = h0(=d_out) + bn(h1), in place -------------
__global__ __launch_bounds__(256) void final_k(
    float* __restrict__ out, const float* __restrict__ h1,
    const float* __restrict__ stats,
    const float* __restrict__ g, const float* __restrict__ bb, int Nn)
{
    long total = (long)Nn * G;
    for (long idx = (long)blockIdx.x * 256 + threadIdx.x; idx < total;
         idx += (long)gridDim.x * 256) {
        int c = (int)(idx % G);
        float mu  = stats[c] / Nn;
        float var = stats[G + c] / Nn - mu * mu;
        float xh  = (h1[idx] - mu) * rsqrtf(var + 1e-5f);
        out[idx] = out[idx] + g[c] * xh + bb[c];
    }
}

extern "C" void kernel_launch(void* const* d_in, const int* in_sizes, int n_in,
                              void* d_out, int out_size, void* d_ws, size_t ws_size,
                              hipStream_t stream)
{
    const float* node_feats = (const float*)d_in[0];
    const float* edge_feats = (const float*)d_in[1];
    const float* gc_node_W  = (const float*)d_in[2];
    const float* gc_node_b  = (const float*)d_in[3];
    const float* gc_e1_W    = (const float*)d_in[4];
    const float* gc_e1_b    = (const float*)d_in[5];
    const float* gc_e2_W    = (const float*)d_in[6];
    const float* gc_e2_b    = (const float*)d_in[7];
    const float* gc_et_W    = (const float*)d_in[8];
    const float* gc_et_b    = (const float*)d_in[9];
    const float* gc_gru_Wx  = (const float*)d_in[10];
    const float* gc_gru_Wh  = (const float*)d_in[11];
    const float* gc_gru_bx  = (const float*)d_in[12];
    const float* gc_gru_bh  = (const float*)d_in[13];
    const float* l1_e_W     = (const float*)d_in[14];
    const float* l1_e_b     = (const float*)d_in[15];
    const float* l1_pn_W    = (const float*)d_in[16];
    const float* l1_pn_b    = (const float*)d_in[17];
    const float* l1_gru_Wx  = (const float*)d_in[18];
    const float* l1_gru_Wh  = (const float*)d_in[19];
    const float* l1_gru_bx  = (const float*)d_in[20];
    const float* l1_gru_bh  = (const float*)d_in[21];
    const float* l1_bn_g    = (const float*)d_in[22];
    const float* l1_bn_b    = (const float*)d_in[23];
    const int*   src        = (const int*)d_in[24];
    const int*   dst        = (const int*)d_in[25];

    const int Nn = in_sizes[0] / NF;
    const int E  = in_sizes[24];

    float* ws = (float*)d_ws;
    size_t o = 0;
    float* hv    = ws + o; o += (size_t)Nn * G;   // hv_new -> hvp -> h1
    float* cbuf  = ws + o; o += (size_t)Nn * G;   // hacc -> et out (in place) -> c2
    float* sden  = ws + o; o += (size_t)Nn;
    float* hd    = ws + o; o += (size_t)Nn;       // hd (layer1) -> hd2 (layer2)
    float* stats = ws + o; o += 512;
    unsigned short* W1t_g   = (unsigned short*)(ws + o); o += (208 * 192) / 2;
    unsigned short* etWt_g  = (unsigned short*)(ws + o); o += (208 * 224) / 2;
    unsigned short* ncWt_g  = (unsigned short*)(ws + o); o += (208 * 128) / 2;
    unsigned short* pnWt_g  = (unsigned short*)(ws + o); o += (208 * 224) / 2;
    unsigned short* Wrzt1_g = (unsigned short*)(ws + o); o += (416 * 416) / 2;
    unsigned short* Wxnt1_g = (unsigned short*)(ws + o); o += (208 * 224) / 2;
    unsigned short* Whnt1_g = (unsigned short*)(ws + o); o += (208 * 224) / 2;
    unsigned short* Wrzt2_g = (unsigned short*)(ws + o); o += (416 * 416) / 2;
    unsigned short* Wxnt2_g = (unsigned short*)(ws + o); o += (208 * 224) / 2;
    unsigned short* Whnt2_g = (unsigned short*)(ws + o); o += (208 * 224) / 2;
    int* cnt    = (int*)(ws + o); o += (size_t)Nn;
    int* offs   = (int*)(ws + o); o += (size_t)Nn + 1;
    int* cursor = (int*)(ws + o); o += (size_t)Nn;
    int* eidC   = (int*)(ws + o); o += (size_t)E;
    int* srcC   = (int*)(ws + o); o += (size_t)E;
    int* dstC   = (int*)(ws + o); o += (size_t)E;
    // total ~22M floats ~= 88 MB (round-5-proven scale)

    float* h0  = (float*)d_out;
    float* hvp = hv;
    float* h1  = hv;

    const int gN64 = (Nn + 63) / 64;
    const int gE64 = (E + 63) / 64;
    const int gE256 = (E + 255) / 256;
    const int nWaves = (Nn + 3) / 4;
    const long totNG = (long)Nn * G;

    // ---------- prep: weights + CSR ----------
    hipMemsetAsync(cnt, 0, (size_t)Nn * sizeof(int), stream);
    tprep_k<<<128, 256, 0, stream>>>(gc_e1_W,   W1t_g,  192, 192, 200, 200);
    tprep_k<<<128, 256, 0, stream>>>(gc_et_W,   etWt_g, 200, 224, 200, 200);
    tprep_k<<<128, 256, 0, stream>>>(gc_node_W, ncWt_g, 128, 128, 200, 200);
    tprep_k<<<128, 256, 0, stream>>>(l1_pn_W,   pnWt_g, 200, 224, 200, 200);
    wprep2_k<<<256, 256, 0, stream>>>(gc_gru_Wx, gc_gru_Wh, Wrzt1_g, Wxnt1_g, Whnt1_g);
    wprep2_k<<<256, 256, 0, stream>>>(l1_gru_Wx, l1_gru_Wh, Wrzt2_g, Wxnt2_g, Whnt2_g);
    hist_k<<<gE256, 256, 0, stream>>>(dst, cnt, E);
    scan_k<<<1, 256, 0, stream>>>(cnt, offs, cursor, Nn);
    scatter_k<<<gE256, 256, 0, stream>>>(src, dst, cursor, eidC, srcC, dstC, E);

    // ---------- GetContext ----------
    hipMemsetAsync(sden, 0, (size_t)Nn * sizeof(float), stream);
    hipMemsetAsync(cbuf, 0, (size_t)Nn * G * sizeof(float), stream);
    hipMemsetAsync(stats, 0, 512 * sizeof(float), stream);

    // hv = leaky(node @ ncW + b)
    mgemm_k<<<gN64, 256, 0, stream>>>(node_feats, ncWt_g, gc_node_b, hv,
                                      Nn, 128, 4, 136, 1, nullptr);
    hd_k<<<nWaves, 256, 0, stream>>>(hv, gc_e2_W, hd, Nn);

    // hacc[dst] += pexp*he1 (segmented), sden[dst] += pexp
    edgefuse2_k<<<gE64, 256, 0, stream>>>(
        node_feats, edge_feats, srcC, dstC, eidC,
        W1t_g, gc_e1_b, gc_e2_W, gc_e2_b, hd, sden, cbuf, E);

    // c = (hacc/sden) @ etW + etb*[deg>0]   (in place on cbuf; et commutes with seg-sum)
    mgemm_k<<<gN64, 256, 0, stream>>>(cbuf, etWt_g, gc_et_b, cbuf,
                                      Nn, 200, 7, 232, 0, sden);

    // h0 = relu(GRU(elu(c), hv))
    grumfma_k<<<gN64, 256, 0, stream>>>(
        cbuf, hv, nullptr, Wrzt1_g, Wxnt1_g, Whnt1_g,
        gc_gru_bx, gc_gru_bh, h0, Nn);

    // ---------- GNNLayer ----------
    hd_k<<<nWaves, 256, 0, stream>>>(h0, l1_e_W, hd, Nn);   // hd2

    // hvp = h0 @ pnW + b
    mgemm_k<<<gN64, 256, 0, stream>>>(h0, pnWt_g, l1_pn_b, hvp,
                                      Nn, 200, 7, 232, 0, nullptr);

    // c2 = sum_e (softmax+1) * hvp[src]  (node-centric, no atomics)
    layer2_k<<<nWaves, 256, 0, stream>>>(h0, hvp, hd, l1_e_W, l1_e_b,
                                         offs, srcC, cbuf, Nn);

    // h1 = relu(GRU(elu(c2), h0))
    grumfma_k<<<gN64, 256, 0, stream>>>(
        cbuf, h0, nullptr, Wrzt2_g, Wxnt2_g, Whnt2_g,
        l1_gru_bx, l1_gru_bh, h1, Nn);

    bnstat_k<<<2048, 256, 0, stream>>>(h1, stats, totNG);
    final_k<<<2048, 256, 0, stream>>>((float*)d_out, h1, stats,
                                      l1_bn_g, l1_bn_b, Nn);
}

// Round 7
// 1123.020 us; speedup vs baseline: 4.0106x; 1.3052x over previous
//
#include <hip/hip_runtime.h>
#include <math.h>

#define G 200
#define NF 128
#define EF 64

typedef __attribute__((ext_vector_type(8))) short bf16x8;
typedef __attribute__((ext_vector_type(4))) float f32x4;

__device__ __forceinline__ float leakyf(float x) { return x > 0.f ? x : 0.01f * x; }
__device__ __forceinline__ float eluf(float x)   { return x > 0.f ? x : (expf(x) - 1.f); }
__device__ __forceinline__ float sigm(float x)   { return 1.f / (1.f + expf(-x)); }

__device__ __forceinline__ unsigned short f2bf(float x) {
    union { float f; unsigned int u; } v; v.f = x;
    unsigned int r = v.u + 0x7FFF + ((v.u >> 16) & 1);   // RNE
    return (unsigned short)(r >> 16);
}
__device__ __forceinline__ float bf2f(unsigned short u) {
    union { unsigned int i; float f; } v; v.i = ((unsigned int)u) << 16;
    return v.f;
}
__device__ __forceinline__ unsigned int pk2(float a, float b) {
    return (unsigned int)f2bf(a) | ((unsigned int)f2bf(b) << 16);
}

// ---------- generic weight transpose+bf16 prep: Wt[208][kpad] = W[k][n] ----------
__global__ __launch_bounds__(256) void tprep_k(
    const float* __restrict__ W, unsigned short* __restrict__ Wt,
    int Kreal, int kpad, int Nstride, int Nreal)
{
    int total = 208 * kpad;
    for (int i = blockIdx.x * 256 + threadIdx.x; i < total; i += gridDim.x * 256) {
        int n = i / kpad, k = i % kpad;
        Wt[i] = (n < Nreal && k < Kreal) ? f2bf(W[(size_t)k * Nstride + n]) : 0;
    }
}

// ---------- GRU weight prep for the tiled GEMM ----------
// Btrz[512][416]: n'<208 -> r gate col c=n'; 208..415 -> z gate col c=n'-208.
//   k<200: Wx[k, gate*200+c]; 208<=k<408: Wh[k-208, gate*200+c]; else 0.
// Btn[512][416]: 16-col subtile s=n'>>4; s even -> gxn chunk s/2; s odd -> ghn.
//   c = (s>>1)*16 + (n'&15). gxn: k<200 -> Wx[k,400+c]. ghn: 208<=k<408 -> Wh[k-208,400+c].
__global__ __launch_bounds__(256) void wgru3_k(
    const float* __restrict__ Wx, const float* __restrict__ Wh,
    unsigned short* __restrict__ Btrz, unsigned short* __restrict__ Btn)
{
    const int total = 512 * 416;
    for (int i = blockIdx.x * 256 + threadIdx.x; i < total; i += gridDim.x * 256) {
        int n = i / 416, k = i % 416;
        float v = 0.f;
        if (n < 416) {
            int gg = (n >= 208) ? 1 : 0;
            int c = n - gg * 208;
            if (c < 200) {
                if (k < 200)                  v = Wx[(size_t)k * 600 + gg * 200 + c];
                else if (k >= 208 && k < 408) v = Wh[(size_t)(k - 208) * 600 + gg * 200 + c];
            }
        }
        Btrz[i] = f2bf(v);

        float u = 0.f;
        int s = n >> 4, cc = n & 15;
        if (s < 26) {
            int c = (s >> 1) * 16 + cc;
            if (c < 200) {
                if (!(s & 1)) { if (k < 200) u = Wx[(size_t)k * 600 + 400 + c]; }
                else { if (k >= 208 && k < 408) u = Wh[(size_t)(k - 208) * 600 + 400 + c]; }
            }
        }
        Btn[i] = f2bf(u);
    }
}

// ---------- A pack: Apk[Mpad][416] bf16 = [elu(X) | pad | H | pad] ----------
__global__ __launch_bounds__(256) void gpack_k(
    const float* __restrict__ X, const float* __restrict__ H,
    unsigned short* __restrict__ Apk, int M, int Mpad)
{
    const long total = (long)Mpad * 52;
    for (long i = (long)blockIdx.x * 256 + threadIdx.x; i < total;
         i += (long)gridDim.x * 256) {
        int row = (int)(i / 52), ch = (int)(i % 52);
        uint4 u = make_uint4(0, 0, 0, 0);
        if (row < M) {
            if (ch < 25) {
                const float4* xp = (const float4*)(X + (size_t)row * 200 + ch * 8);
                float4 a = xp[0], b = xp[1];
                u.x = pk2(eluf(a.x), eluf(a.y)); u.y = pk2(eluf(a.z), eluf(a.w));
                u.z = pk2(eluf(b.x), eluf(b.y)); u.w = pk2(eluf(b.z), eluf(b.w));
            } else if (ch >= 26 && ch < 51) {
                const float4* hp = (const float4*)(H + (size_t)row * 200 + (ch - 26) * 8);
                float4 a = hp[0], b = hp[1];
                u.x = pk2(a.x, a.y); u.y = pk2(a.z, a.w);
                u.z = pk2(b.x, b.y); u.w = pk2(b.z, b.w);
            }
        }
        *(uint4*)&Apk[(size_t)row * 416 + ch * 8] = u;
    }
}

// ---------- tiled 128x128 GEMM, K=416, double-buffered LDS, bf16 MFMA ----------
// EPI 0: RZ[row*416+col] = bf16(sigm(acc + bias))          (rz pass)
// EPI 1: full GRU n-combine -> OUT[row*200+c] = relu((1-z)n + z*h)
template <int EPI>
__global__ __launch_bounds__(256) void tgemm_k(
    const unsigned short* __restrict__ Apk,  // [Mpad][416] bf16
    const unsigned short* __restrict__ Bt,   // [512][416] bf16
    const float* __restrict__ bx, const float* __restrict__ bh,
    unsigned short* __restrict__ RZ,         // EPI0 out / EPI1 in
    float* __restrict__ OUT, int M)
{
    __shared__ __align__(16) unsigned short As[2][128 * 32];
    __shared__ __align__(16) unsigned short Bs[2][128 * 32];

    const int tid = threadIdx.x;
    const int w = tid >> 6, lane = tid & 63, l15 = lane & 15, lq = lane >> 4;
    const int wr = w >> 1, wc = w & 1;
    const int bm = blockIdx.x * 128, bn = blockIdx.y * 128;
    const int r0 = tid >> 2, sl = tid & 3;

    f32x4 acc[4][4];
#pragma unroll
    for (int a = 0; a < 4; ++a)
#pragma unroll
        for (int b = 0; b < 4; ++b) acc[a][b] = (f32x4){0.f, 0.f, 0.f, 0.f};

    // prologue: stage chunk 0
    {
        uint4 pa0 = *(const uint4*)&Apk[(size_t)(bm + r0) * 416 + sl * 8];
        uint4 pa1 = *(const uint4*)&Apk[(size_t)(bm + 64 + r0) * 416 + sl * 8];
        uint4 pb0 = *(const uint4*)&Bt[(size_t)(bn + r0) * 416 + sl * 8];
        uint4 pb1 = *(const uint4*)&Bt[(size_t)(bn + 64 + r0) * 416 + sl * 8];
        int w0 = sl ^ ((r0 >> 1) & 3), w1 = sl ^ (((r0 + 64) >> 1) & 3);
        *(uint4*)&As[0][r0 * 32 + w0 * 8] = pa0;
        *(uint4*)&As[0][(r0 + 64) * 32 + w1 * 8] = pa1;
        *(uint4*)&Bs[0][r0 * 32 + w0 * 8] = pb0;
        *(uint4*)&Bs[0][(r0 + 64) * 32 + w1 * 8] = pb1;
    }
    __syncthreads();

    int cur = 0;
    for (int c = 0; c < 13; ++c) {
        uint4 pa0, pa1, pb0, pb1;
        if (c < 12) {
            int kc = (c + 1) * 32;
            pa0 = *(const uint4*)&Apk[(size_t)(bm + r0) * 416 + kc + sl * 8];
            pa1 = *(const uint4*)&Apk[(size_t)(bm + 64 + r0) * 416 + kc + sl * 8];
            pb0 = *(const uint4*)&Bt[(size_t)(bn + r0) * 416 + kc + sl * 8];
            pb1 = *(const uint4*)&Bt[(size_t)(bn + 64 + r0) * 416 + kc + sl * 8];
        }
        // compute on cur
        bf16x8 af[4], bfr[4];
#pragma unroll
        for (int s = 0; s < 4; ++s) {
            int ra = wr * 64 + s * 16 + l15;
            af[s] = *(const bf16x8*)&As[cur][ra * 32 + (lq ^ ((ra >> 1) & 3)) * 8];
            int rb = wc * 64 + s * 16 + l15;
            bfr[s] = *(const bf16x8*)&Bs[cur][rb * 32 + (lq ^ ((rb >> 1) & 3)) * 8];
        }
#pragma unroll
        for (int sr = 0; sr < 4; ++sr)
#pragma unroll
            for (int sc = 0; sc < 4; ++sc)
                acc[sr][sc] = __builtin_amdgcn_mfma_f32_16x16x32_bf16(
                    af[sr], bfr[sc], acc[sr][sc], 0, 0, 0);

        if (c < 12) {
            int nb = cur ^ 1;
            int w0 = sl ^ ((r0 >> 1) & 3), w1 = sl ^ (((r0 + 64) >> 1) & 3);
            *(uint4*)&As[nb][r0 * 32 + w0 * 8] = pa0;
            *(uint4*)&As[nb][(r0 + 64) * 32 + w1 * 8] = pa1;
            *(uint4*)&Bs[nb][r0 * 32 + w0 * 8] = pb0;
            *(uint4*)&Bs[nb][(r0 + 64) * 32 + w1 * 8] = pb1;
        }
        __syncthreads();
        cur ^= 1;
    }

    if (EPI == 0) {
#pragma unroll
        for (int sr = 0; sr < 4; ++sr)
#pragma unroll
            for (int sc = 0; sc < 4; ++sc) {
                int col = bn + wc * 64 + sc * 16 + l15;
                if (col >= 416) continue;
                float bsum = (col < 208) ? (bx[col] + bh[col])
                                         : (bx[col - 8] + bh[col - 8]);
#pragma unroll
                for (int i = 0; i < 4; ++i) {
                    int row = bm + wr * 64 + sr * 16 + lq * 4 + i;
                    if (row < M)
                        RZ[(size_t)row * 416 + col] = f2bf(sigm(acc[sr][sc][i] + bsum));
                }
            }
    } else {
#pragma unroll
        for (int p = 0; p < 2; ++p) {
            int sglob = (bn >> 4) + wc * 4 + 2 * p;
            int cc = (sglob >> 1) * 16 + l15;
            if (cc >= 200) continue;
            float bxn = bx[400 + cc], bhn = bh[400 + cc];
#pragma unroll
            for (int sr = 0; sr < 4; ++sr)
#pragma unroll
                for (int i = 0; i < 4; ++i) {
                    int row = bm + wr * 64 + sr * 16 + lq * 4 + i;
                    if (row >= M) continue;
                    float rr = bf2f(RZ[(size_t)row * 416 + cc]);
                    float zz = bf2f(RZ[(size_t)row * 416 + 208 + cc]);
                    float hh = bf2f(Apk[(size_t)row * 416 + 208 + cc]);
                    float nn = tanhf(acc[sr][2 * p][i] + bxn +
                                     rr * (acc[sr][2 * p + 1][i] + bhn));
                    float o = (1.f - zz) * nn + zz * hh;
                    OUT[(size_t)row * 200 + cc] = fmaxf(o, 0.f);
                }
        }
    }
}

// ---------- CSR build ----------
__global__ __launch_bounds__(256) void hist_k(
    const int* __restrict__ dst, int* __restrict__ cnt, int E)
{
    int i = blockIdx.x * 256 + threadIdx.x;
    if (i < E) atomicAdd(&cnt[dst[i]], 1);
}

__global__ __launch_bounds__(256) void scan_k(
    const int* __restrict__ cnt, int* __restrict__ offs,
    int* __restrict__ cursor, int Nn)
{
    __shared__ int wsum[4];
    const int tid = threadIdx.x;
    const int lane = tid & 63, wv = tid >> 6;
    int carry = 0;
    const int CH = 8;
    for (int base = 0; base < Nn; base += 256 * CH) {
        int v[CH]; int tsum = 0;
        int i0 = base + tid * CH;
#pragma unroll
        for (int j = 0; j < CH; ++j) {
            v[j] = (i0 + j < Nn) ? cnt[i0 + j] : 0;
            tsum += v[j];
        }
        int x = tsum;
        for (int off = 1; off < 64; off <<= 1) {
            int t = __shfl_up(x, off);
            if (lane >= off) x += t;
        }
        if (lane == 63) wsum[wv] = x;
        __syncthreads();
        int wbase = 0;
#pragma unroll
        for (int wq = 0; wq < 4; ++wq) wbase += (wq < wv) ? wsum[wq] : 0;
        int gtot = wsum[0] + wsum[1] + wsum[2] + wsum[3];
        int run = carry + wbase + (x - tsum);
#pragma unroll
        for (int j = 0; j < CH; ++j) {
            int idx = i0 + j;
            if (idx < Nn) { offs[idx] = run; cursor[idx] = run; }
            run += v[j];
        }
        carry += gtot;
        __syncthreads();
    }
    if (tid == 0) offs[Nn] = carry;
}

__global__ __launch_bounds__(256) void scatter_k(
    const int* __restrict__ src, const int* __restrict__ dst,
    int* __restrict__ cursor, int* __restrict__ eidC,
    int* __restrict__ srcC, int* __restrict__ dstC, int E)
{
    int i = blockIdx.x * 256 + threadIdx.x;
    if (i < E) {
        int d = dst[i];
        int pos = atomicAdd(&cursor[d], 1);
        eidC[pos] = i; srcC[pos] = src[i]; dstC[pos] = d;
    }
}

// ---------- dense MFMA GEMM (64-row): OUT[M,200] = epi((X/xdiv) @ W + bias*gate) ----------
__global__ __launch_bounds__(256) void mgemm_k(
    const float* __restrict__ X, const unsigned short* __restrict__ Wt,
    const float* __restrict__ bias, float* __restrict__ OUT,
    int M, int Kreal, int kch, int astr, int leaky,
    const float* __restrict__ xdiv)
{
    __shared__ __align__(16) unsigned short A[64 * 232];
    const int tid = threadIdx.x;
    const int w = tid >> 6, lane = tid & 63, l15 = lane & 15, lq = lane >> 4;
    const int bm = blockIdx.x * 64;
    const int kpad = kch * 32;
    const int nch8 = Kreal >> 3;

    for (int i = tid; i < 64 * nch8; i += 256) {
        int r = i / nch8, ch = i % nch8;
        int grow = bm + r;
        uint4 u = make_uint4(0, 0, 0, 0);
        if (grow < M) {
            const float4* xp = (const float4*)(X + (size_t)grow * Kreal + ch * 8);
            float inv = 1.f;
            if (xdiv) { float dv = xdiv[grow]; inv = (dv > 0.f) ? 1.f / dv : 0.f; }
            float4 a = xp[0], b = xp[1];
            u.x = pk2(a.x * inv, a.y * inv); u.y = pk2(a.z * inv, a.w * inv);
            u.z = pk2(b.x * inv, b.y * inv); u.w = pk2(b.z * inv, b.w * inv);
        }
        *(uint4*)&A[r * astr + ch * 8] = u;
    }
    if (tid < 64) {
        for (int p = Kreal; p < kpad; p += 8)
            *(uint4*)&A[tid * astr + p] = make_uint4(0, 0, 0, 0);
    }
    __syncthreads();

    const int arow = (w * 16 + l15) * astr;
    f32x4 acc[13];
#pragma unroll
    for (int t = 0; t < 13; ++t) acc[t] = (f32x4){0.f, 0.f, 0.f, 0.f};

    for (int c = 0; c < kch; ++c) {
        bf16x8 a = *(const bf16x8*)&A[arow + c * 32 + lq * 8];
#pragma unroll
        for (int t = 0; t < 13; ++t) {
            bf16x8 b = *(const bf16x8*)&Wt[(size_t)(t * 16 + l15) * kpad + c * 32 + lq * 8];
            acc[t] = __builtin_amdgcn_mfma_f32_16x16x32_bf16(a, b, acc[t], 0, 0, 0);
        }
    }

    float rg[4];
#pragma unroll
    for (int i = 0; i < 4; ++i) {
        int grow = bm + w * 16 + lq * 4 + i;
        rg[i] = 1.f;
        if (xdiv && grow < M) rg[i] = (xdiv[grow] > 0.f) ? 1.f : 0.f;
    }

#pragma unroll
    for (int t = 0; t < 13; ++t) {
        int col = t * 16 + l15;
        if (col >= 200) continue;
        float bs = bias[col];
#pragma unroll
        for (int i = 0; i < 4; ++i) {
            int grow = bm + w * 16 + lq * 4 + i;
            if (grow >= M) continue;
            float v = acc[t][i] + bs * rg[i];
            OUT[(size_t)grow * 200 + col] = leaky ? leakyf(v) : v;
        }
    }
}

// ---------------- hd[n] = x[n,:] . W[0:200] ----------------
__global__ __launch_bounds__(256) void hd_k(
    const float* __restrict__ x, const float* __restrict__ W,
    float* __restrict__ hd, int Nn)
{
    int wid = blockIdx.x * 4 + (threadIdx.x >> 6);
    int lane = threadIdx.x & 63;
    if (wid >= Nn) return;
    float s = 0.f;
    for (int j = lane; j < G; j += 64) s += x[(size_t)wid * G + j] * W[j];
    for (int off = 32; off; off >>= 1) s += __shfl_down(s, off);
    if (lane == 0) hd[wid] = s;
}

// ============ fused edge kernel (CSR order, MFMA bf16) ============
__global__ __launch_bounds__(256) void edgefuse2_k(
    const float* __restrict__ node, const float* __restrict__ edgef,
    const int* __restrict__ srcC, const int* __restrict__ dstC,
    const int* __restrict__ eidC,
    const unsigned short* __restrict__ W1t, const float* __restrict__ b1,
    const float* __restrict__ e2W, const float* __restrict__ e2b,
    const float* __restrict__ hd,
    float* __restrict__ sden, float* __restrict__ hacc, int E)
{
    __shared__ __align__(16) unsigned short U[64 * 216];
    __shared__ __align__(16) unsigned short Wt[208 * 40];
    __shared__ float rowlg[64];
    __shared__ float pexp_s[64];
    __shared__ int   dst_s[64];

    const int tid  = threadIdx.x;
    const int w    = tid >> 6;
    const int lane = tid & 63;
    const int l15  = lane & 15;
    const int lq   = lane >> 4;
    const int eb   = blockIdx.x * 64;

    {
        const int r4 = tid >> 2, q = tid & 3;
        const int pos = eb + r4;
        if (pos < E) {
            const int se = srcC[pos];
            const int ei = eidC[pos];
            const float4* np = (const float4*)(node + (size_t)se * NF);
            const float4* ep = (const float4*)(edgef + (size_t)ei * EF);
            uint4* rowp = (uint4*)(U + r4 * 216);
#pragma unroll
            for (int i = 0; i < 4; ++i) {
                float4 a = np[q * 8 + 2 * i];
                float4 b = np[q * 8 + 2 * i + 1];
                uint4 u; u.x = pk2(a.x, a.y); u.y = pk2(a.z, a.w);
                u.z = pk2(b.x, b.y); u.w = pk2(b.z, b.w);
                rowp[q * 4 + i] = u;
            }
            uint4* edp = (uint4*)(U + r4 * 216 + 128);
#pragma unroll
            for (int i = 0; i < 2; ++i) {
                float4 a = ep[q * 4 + 2 * i];
                float4 b = ep[q * 4 + 2 * i + 1];
                uint4 u; u.x = pk2(a.x, a.y); u.y = pk2(a.z, a.w);
                u.z = pk2(b.x, b.y); u.w = pk2(b.z, b.w);
                edp[q * 2 + i] = u;
            }
        } else {
            uint4 z = make_uint4(0, 0, 0, 0);
            uint4* rowp = (uint4*)(U + r4 * 216);
#pragma unroll
            for (int i = 0; i < 4; ++i) rowp[q * 4 + i] = z;
            uint4* edp = (uint4*)(U + r4 * 216 + 128);
            edp[q * 2] = z; edp[q * 2 + 1] = z;
        }
        if (tid < 64) dst_s[tid] = (eb + tid < E) ? dstC[eb + tid] : -1;
    }
    __syncthreads();

    f32x4 acc[13];
#pragma unroll
    for (int t = 0; t < 13; ++t) acc[t] = (f32x4){0.f, 0.f, 0.f, 0.f};

    for (int c = 0; c < 6; ++c) {
        for (int q = tid; q < 832; q += 256) {
            int n = q >> 2, s = q & 3;
            *(uint4*)(Wt + n * 40 + s * 8) =
                *(const uint4*)(W1t + (size_t)n * 192 + c * 32 + s * 8);
        }
        __syncthreads();
        bf16x8 a = *(const bf16x8*)(U + (w * 16 + l15) * 216 + c * 32 + lq * 8);
#pragma unroll
        for (int t = 0; t < 13; ++t) {
            bf16x8 b = *(const bf16x8*)(Wt + (t * 16 + l15) * 40 + lq * 8);
            acc[t] = __builtin_amdgcn_mfma_f32_16x16x32_bf16(a, b, acc[t], 0, 0, 0);
        }
        __syncthreads();
    }

    float p[4] = {0.f, 0.f, 0.f, 0.f};
#pragma unroll
    for (int t = 0; t < 13; ++t) {
        const int col = t * 16 + l15;
#pragma unroll
        for (int r = 0; r < 4; ++r) {
            const int row = w * 16 + lq * 4 + r;
            float v = 0.f;
            if (col < 200) {
                v = leakyf(acc[t][r] + b1[col]);
                p[r] = fmaf(v, e2W[200 + col], p[r]);
            }
            U[row * 216 + col] = f2bf(v);
        }
    }
#pragma unroll
    for (int r = 0; r < 4; ++r) {
        p[r] += __shfl_xor(p[r], 1);
        p[r] += __shfl_xor(p[r], 2);
        p[r] += __shfl_xor(p[r], 4);
        p[r] += __shfl_xor(p[r], 8);
    }
    if (l15 == 0) {
#pragma unroll
        for (int r = 0; r < 4; ++r) rowlg[w * 16 + lq * 4 + r] = p[r];
    }
    __syncthreads();

    if (tid < 64) {
        float pe = 0.f;
        if (eb + tid < E) {
            float l = leakyf(rowlg[tid] + hd[dst_s[tid]] + e2b[0]);
            pe = expf(l);
            atomicAdd(&sden[dst_s[tid]], pe);
        }
        pexp_s[tid] = pe;
    }
    __syncthreads();

    if (tid < 200) {
        const int c = tid;
        float s = 0.f;
        int cur = dst_s[0];
        for (int r = 0; r < 64; ++r) {
            int d = dst_s[r];
            if (d < 0) break;
            if (d != cur) {
                atomicAdd(&hacc[(size_t)cur * 200 + c], s);
                s = 0.f; cur = d;
            }
            s = fmaf(pexp_s[r], bf2f(U[r * 216 + c]), s);
        }
        atomicAdd(&hacc[(size_t)cur * 200 + c], s);
    }
}

// ============ layer-2: node-centric logits + softmax + c2 gather (no atomics) ============
__global__ __launch_bounds__(256) void layer2_k(
    const float* __restrict__ h0, const float* __restrict__ hvp,
    const float* __restrict__ hd2,
    const float* __restrict__ W, const float* __restrict__ b,
    const int* __restrict__ offs, const int* __restrict__ srcC,
    float* __restrict__ c2, int Nn)
{
    __shared__ float pes[4][64];
    const int wv = threadIdx.x >> 6;
    const int lane = threadIdx.x & 63;
    const int n = blockIdx.x * 4 + wv;
    if (n >= Nn) return;

    const int base = offs[n], end = offs[n + 1];
    const float hdn = hd2[n] + b[0];

    float ssum = 0.f;
    for (int pos = base; pos < end; ++pos) {
        const float* hr = h0 + (size_t)srcC[pos] * 200;
        float part = hr[lane] * W[200 + lane]
                   + hr[64 + lane] * W[264 + lane]
                   + hr[128 + lane] * W[328 + lane];
        if (lane < 8) part += hr[192 + lane] * W[392 + lane];
        for (int off = 32; off; off >>= 1) part += __shfl_xor(part, off);
        float pe = expf(leakyf(part + hdn));
        ssum += pe;
        int i = pos - base;
        if (i < 64 && lane == 0) pes[wv][i] = pe;
    }
    float inv = (end > base) ? 1.f / ssum : 0.f;

    float a0 = 0.f, a1 = 0.f, a2v = 0.f, a3 = 0.f;
    for (int pos = base; pos < end; ++pos) {
        int i = pos - base;
        float pe;
        if (i < 64) pe = pes[wv][i];
        else {
            const float* hr = h0 + (size_t)srcC[pos] * 200;
            float part = hr[lane] * W[200 + lane]
                       + hr[64 + lane] * W[264 + lane]
                       + hr[128 + lane] * W[328 + lane];
            if (lane < 8) part += hr[192 + lane] * W[392 + lane];
            for (int off = 32; off; off >>= 1) part += __shfl_xor(part, off);
            pe = expf(leakyf(part + hdn));
        }
        float aw = pe * inv + 1.f;
        const float* vr = hvp + (size_t)srcC[pos] * 200;
        a0  += aw * vr[lane];
        a1  += aw * vr[64 + lane];
        a2v += aw * vr[128 + lane];
        if (lane < 8) a3 += aw * vr[192 + lane];
    }
    float* out = c2 + (size_t)n * 200;
    out[lane] = a0; out[64 + lane] = a1; out[128 + lane] = a2v;
    if (lane < 8) out[192 + lane] = a3;
}

// ------------- batchnorm stats -------------
__global__ __launch_bounds__(256) void bnstat_k(
    const float* __restrict__ h1, float* __restrict__ stats, long total)
{
    __shared__ float ls[2 * G];
    for (int t = threadIdx.x; t < 2 * G; t += 256) ls[t] = 0.f;
    __syncthreads();
    for (long idx = (long)blockIdx.x * 256 + threadIdx.x; idx < total;
         idx += (long)gridDim.x * 256) {
        float v = h1[idx];
        int c = (int)(idx % G);
        atomicAdd(&ls[c], v);
        atomicAdd(&ls[G + c], v * v);
    }
    __syncthreads();
    for (int t = threadIdx.x; t < 2 * G; t += 256) atomicAdd(&stats[t], ls[t]);
}

// ------------- out = h0(=d_out) + bn(h1), in place -------------
__global__ __launch_bounds__(256) void final_k(
    float* __restrict__ out, const float* __restrict__ h1,
    const float* __restrict__ stats,
    const float* __restrict__ g, const float* __restrict__ bb, int Nn)
{
    long total = (long)Nn * G;
    for (long idx = (long)blockIdx.x * 256 + threadIdx.x; idx < total;
         idx += (long)gridDim.x * 256) {
        int c = (int)(idx % G);
        float mu  = stats[c] / Nn;
        float var = stats[G + c] / Nn - mu * mu;
        float xh  = (h1[idx] - mu) * rsqrtf(var + 1e-5f);
        out[idx] = out[idx] + g[c] * xh + bb[c];
    }
}

extern "C" void kernel_launch(void* const* d_in, const int* in_sizes, int n_in,
                              void* d_out, int out_size, void* d_ws, size_t ws_size,
                              hipStream_t stream)
{
    const float* node_feats = (const float*)d_in[0];
    const float* edge_feats = (const float*)d_in[1];
    const float* gc_node_W  = (const float*)d_in[2];
    const float* gc_node_b  = (const float*)d_in[3];
    const float* gc_e1_W    = (const float*)d_in[4];
    const float* gc_e1_b    = (const float*)d_in[5];
    const float* gc_e2_W    = (const float*)d_in[6];
    const float* gc_e2_b    = (const float*)d_in[7];
    const float* gc_et_W    = (const float*)d_in[8];
    const float* gc_et_b    = (const float*)d_in[9];
    const float* gc_gru_Wx  = (const float*)d_in[10];
    const float* gc_gru_Wh  = (const float*)d_in[11];
    const float* gc_gru_bx  = (const float*)d_in[12];
    const float* gc_gru_bh  = (const float*)d_in[13];
    const float* l1_e_W     = (const float*)d_in[14];
    const float* l1_e_b     = (const float*)d_in[15];
    const float* l1_pn_W    = (const float*)d_in[16];
    const float* l1_pn_b    = (const float*)d_in[17];
    const float* l1_gru_Wx  = (const float*)d_in[18];
    const float* l1_gru_Wh  = (const float*)d_in[19];
    const float* l1_gru_bx  = (const float*)d_in[20];
    const float* l1_gru_bh  = (const float*)d_in[21];
    const float* l1_bn_g    = (const float*)d_in[22];
    const float* l1_bn_b    = (const float*)d_in[23];
    const int*   src        = (const int*)d_in[24];
    const int*   dst        = (const int*)d_in[25];

    const int Nn = in_sizes[0] / NF;
    const int E  = in_sizes[24];
    const int Mpad = ((Nn + 127) / 128) * 128;

    float* ws = (float*)d_ws;
    size_t o = 0;
    float* hv    = ws + o; o += (size_t)Nn * G;        // hv_new -> hvp -> h1
    float* cbuf  = ws + o; o += ((size_t)Mpad * 416 + 1) / 2;  // hacc/c/c2 + rzbuf overlay
    unsigned short* rzbuf = (unsigned short*)cbuf;
    float* sden  = ws + o; o += (size_t)Nn;
    float* hd    = ws + o; o += (size_t)Nn;
    float* stats = ws + o; o += 512;
    unsigned short* W1t_g  = (unsigned short*)(ws + o); o += (208 * 192) / 2;
    unsigned short* etWt_g = (unsigned short*)(ws + o); o += (208 * 224) / 2;
    unsigned short* ncWt_g = (unsigned short*)(ws + o); o += (208 * 128) / 2;
    unsigned short* pnWt_g = (unsigned short*)(ws + o); o += (208 * 224) / 2;
    unsigned short* Btrz1  = (unsigned short*)(ws + o); o += (512 * 416) / 2;
    unsigned short* Btn1   = (unsigned short*)(ws + o); o += (512 * 416) / 2;
    unsigned short* Btrz2  = (unsigned short*)(ws + o); o += (512 * 416) / 2;
    unsigned short* Btn2   = (unsigned short*)(ws + o); o += (512 * 416) / 2;
    int* cnt    = (int*)(ws + o); o += (size_t)Nn;
    int* offs   = (int*)(ws + o); o += (size_t)Nn + 1;
    int* cursor = (int*)(ws + o); o += (size_t)Nn;
    int* eidC   = (int*)(ws + o); o += (size_t)E;
    int* srcC   = (int*)(ws + o); o += (size_t)E;
    int* dstC   = (int*)(ws + o); o += (size_t)E;
    unsigned short* apack = (unsigned short*)(ws + o); o += ((size_t)Mpad * 416 + 1) / 2;
    // total ~36M floats ~= 144 MB

    float* h0  = (float*)d_out;
    float* hvp = hv;
    float* h1  = hv;

    const int gN64 = (Nn + 63) / 64;
    const int gE64 = (E + 63) / 64;
    const int gE256 = (E + 255) / 256;
    const int nWaves = (Nn + 3) / 4;
    const long totNG = (long)Nn * G;
    const dim3 gGEMM((Mpad / 128), 4);

    // ---------- prep: weights + CSR ----------
    hipMemsetAsync(cnt, 0, (size_t)Nn * sizeof(int), stream);
    tprep_k<<<128, 256, 0, stream>>>(gc_e1_W,   W1t_g,  192, 192, 200, 200);
    tprep_k<<<128, 256, 0, stream>>>(gc_et_W,   etWt_g, 200, 224, 200, 200);
    tprep_k<<<128, 256, 0, stream>>>(gc_node_W, ncWt_g, 128, 128, 200, 200);
    tprep_k<<<128, 256, 0, stream>>>(l1_pn_W,   pnWt_g, 200, 224, 200, 200);
    wgru3_k<<<256, 256, 0, stream>>>(gc_gru_Wx, gc_gru_Wh, Btrz1, Btn1);
    wgru3_k<<<256, 256, 0, stream>>>(l1_gru_Wx, l1_gru_Wh, Btrz2, Btn2);
    hist_k<<<gE256, 256, 0, stream>>>(dst, cnt, E);
    scan_k<<<1, 256, 0, stream>>>(cnt, offs, cursor, Nn);
    scatter_k<<<gE256, 256, 0, stream>>>(src, dst, cursor, eidC, srcC, dstC, E);

    // ---------- GetContext ----------
    hipMemsetAsync(sden, 0, (size_t)Nn * sizeof(float), stream);
    hipMemsetAsync(cbuf, 0, (size_t)Nn * G * sizeof(float), stream);
    hipMemsetAsync(stats, 0, 512 * sizeof(float), stream);

    // hv = leaky(node @ ncW + b)
    mgemm_k<<<gN64, 256, 0, stream>>>(node_feats, ncWt_g, gc_node_b, hv,
                                      Nn, 128, 4, 136, 1, nullptr);
    hd_k<<<nWaves, 256, 0, stream>>>(hv, gc_e2_W, hd, Nn);

    // hacc[dst] += pexp*he1 (segmented), sden[dst] += pexp
    edgefuse2_k<<<gE64, 256, 0, stream>>>(
        node_feats, edge_feats, srcC, dstC, eidC,
        W1t_g, gc_e1_b, gc_e2_W, gc_e2_b, hd, sden, cbuf, E);

    // c = (hacc/sden) @ etW + etb*[deg>0]
    mgemm_k<<<gN64, 256, 0, stream>>>(cbuf, etWt_g, gc_et_b, cbuf,
                                      Nn, 200, 7, 232, 0, sden);

    // ---- GRU1: h0 = relu(GRU(elu(c), hv)) via pack + 2 tiled GEMMs ----
    gpack_k<<<2048, 256, 0, stream>>>(cbuf, hv, apack, Nn, Mpad);
    tgemm_k<0><<<gGEMM, 256, 0, stream>>>(apack, Btrz1, gc_gru_bx, gc_gru_bh,
                                          rzbuf, nullptr, Nn);
    tgemm_k<1><<<gGEMM, 256, 0, stream>>>(apack, Btn1, gc_gru_bx, gc_gru_bh,
                                          rzbuf, h0, Nn);

    // ---------- GNNLayer ----------
    hd_k<<<nWaves, 256, 0, stream>>>(h0, l1_e_W, hd, Nn);   // hd2

    // hvp = h0 @ pnW + b
    mgemm_k<<<gN64, 256, 0, stream>>>(h0, pnWt_g, l1_pn_b, hvp,
                                      Nn, 200, 7, 232, 0, nullptr);

    // c2 = sum_e (softmax+1) * hvp[src]  (node-centric, no atomics)
    layer2_k<<<nWaves, 256, 0, stream>>>(h0, hvp, hd, l1_e_W, l1_e_b,
                                         offs, srcC, cbuf, Nn);

    // ---- GRU2: h1 = relu(GRU(elu(c2), h0)) ----
    gpack_k<<<2048, 256, 0, stream>>>(cbuf, h0, apack, Nn, Mpad);
    tgemm_k<0><<<gGEMM, 256, 0, stream>>>(apack, Btrz2, l1_gru_bx, l1_gru_bh,
                                          rzbuf, nullptr, Nn);
    tgemm_k<1><<<gGEMM, 256, 0, stream>>>(apack, Btn2, l1_gru_bx, l1_gru_bh,
                                          rzbuf, h1, Nn);

    bnstat_k<<<2048, 256, 0, stream>>>(h1, stats, totNG);
    final_k<<<2048, 256, 0, stream>>>((float*)d_out, h1, stats,
                                      l1_bn_g, l1_bn_b, Nn);
}